// Round 13
// baseline (3443.628 us; speedup 1.0000x reference)
//
#include <hip/hip_runtime.h>
#include <cstdint>
#include <cstddef>

// ---------------- problem constants ----------------
#define B_     16
#define T_     8000
#define TN_    800
#define HID_   512
#define L_     128
#define KCB_   1024
#define Q_     4
#define COUNT_ 1599
#define NC_    (B_*COUNT_)   // 25584
#define NTOK_  (B_*T_)       // 128000
#define EPSF   1e-12

// decoder GEMM dims
#define KP1_   672           // k' = u*132 + ci (660 meaningful), padded to 672
#define NN1_   2560
#define KP2_   2560
#define NN2_   640

// conv2a/2b MFMA dims
#define ZROWS_ 8072          // upsampled rows: t in [-2, 8069]; row = t + 2
#define ZROWU_ 1024          // u16 per row: [pl(2)][ci(512)]
#define Z2ROWS_ 8072ull      // z2t rows: row = t + 3, pads zeroed
#define Z2ROWU_ 1024ull

typedef float v2f __attribute__((ext_vector_type(2)));
typedef short s16x8 __attribute__((ext_vector_type(8)));
typedef float f32x4 __attribute__((ext_vector_type(4)));
#define PKFMA(a,b,c) __builtin_elementwise_fma((a),(b),(c))
#define MFMA16(a,b,c) __builtin_amdgcn_mfma_f32_16x16x32_bf16((a),(b),(c),0,0,0)

// ---------------- static workspace layout (float offsets) ----------------
#define OFF_WT1   0ull
#define OFF_WT2A  30720ull        // Wp2a bf16 planes [512co][2][2560] = 1310720 floats
#define OFF_WT2B  1341440ull      // Wp2b bf16 planes [128co][2][3584] = 458752 floats
#define OFF_W1E   1800192ull
#define OFF_W2E   3520512ull
#define OFF_CBT   5158912ull      // cbp bf16 planes [q][pl][kb][1024 codes][8] = 524288 floats
#define OFF_CNORM 5683200ull
#define OFF_CNF   5691392ull
#define OFF_SCAL  5695488ull
#define OFF_X1    5697536ull
#define OFF_CODES 5953536ull
#define OFF_ZE    6465536ull
#define OFF_SCR   22849536ull

// ---------------- helpers ----------------
__device__ inline float wred(float v){
    #pragma unroll
    for (int o = 32; o > 0; o >>= 1) v += __shfl_xor(v, o);
    return v;
}
__device__ inline double shflxor_d(double v, int m){
    int2 a = *(int2*)&v;
    a.x = __shfl_xor(a.x, m);
    a.y = __shfl_xor(a.y, m);
    return *(double*)&a;
}
__device__ inline double wredd(double v){
    #pragma unroll
    for (int o = 32; o > 0; o >>= 1) v += shflxor_d(v, o);
    return v;
}
__device__ inline double qred(double v){
    v += shflxor_d(v, 1);
    v += shflxor_d(v, 2);
    return v;
}
// split fp32 into bf16 hi/lo (RNE): x ~= hi + lo, |err| <= 2^-18 |x|
__device__ inline void bsplit(float x, unsigned short &h, unsigned short &l){
    unsigned u = __float_as_uint(x);
    unsigned hr = (u + 0x7fffu + ((u >> 16) & 1u)) >> 16;
    float hf = __uint_as_float(hr << 16);
    h = (unsigned short)hr;
    float r = x - hf;
    unsigned u2 = __float_as_uint(r);
    unsigned lr2 = (u2 + 0x7fffu + ((u2 >> 16) & 1u)) >> 16;
    l = (unsigned short)lr2;
}

// ---------------- small prep kernels ----------------
__global__ __launch_bounds__(256) void k_zero(float* s){
    s[blockIdx.x*256 + threadIdx.x] = 0.f;
}

__global__ __launch_bounds__(256) void k_wtrans(const float* __restrict__ w, float* __restrict__ wT,
                                                int Cin, int K, int CO, int total){
    int i = blockIdx.x*256 + threadIdx.x;
    if (i >= total) return;
    int ci = i / (K*CO); int r = i % (K*CO); int k = r / CO; int co = r % CO;
    wT[i] = w[((size_t)co*Cin + ci)*K + k];
}

// conv2a weights -> [co][pl][kdim = u*512 + ci] bf16 hi/lo planes
__global__ __launch_bounds__(256) void k_wprep2a(const float* __restrict__ w, unsigned short* __restrict__ Wp){
    int idx = blockIdx.x*256 + threadIdx.x;   // 512*2560
    if (idx >= 512*2560) return;
    int co = idx / 2560, kd = idx % 2560;
    int u = kd >> 9, ci = kd & 511;
    float v = w[((size_t)co*512 + ci)*5 + u];
    unsigned short h, l; bsplit(v, h, l);
    Wp[((size_t)co*2 + 0)*2560 + kd] = h;
    Wp[((size_t)co*2 + 1)*2560 + kd] = l;
}

// conv2b weights -> [co][pl][kdim = u*512 + ci] bf16 hi/lo planes (K=7)
__global__ __launch_bounds__(256) void k_wprep2b(const float* __restrict__ w, unsigned short* __restrict__ Wp){
    int idx = blockIdx.x*256 + threadIdx.x;   // 128*3584
    if (idx >= 128*3584) return;
    int co = idx / 3584, kd = idx % 3584;
    int u = kd / 512, ci = kd % 512;
    float v = w[((size_t)co*512 + ci)*7 + u];
    unsigned short h, l; bsplit(v, h, l);
    Wp[((size_t)co*2 + 0)*3584 + kd] = h;
    Wp[((size_t)co*2 + 1)*3584 + kd] = l;
}

// GEMM1 decoder weights -> [n][pl][k' = u*132 + ci] bf16 hi/lo (coalescing-friendly enum)
__global__ __launch_bounds__(256) void k_wexpand2a(const float* __restrict__ w, unsigned short* __restrict__ Bp){
    int idx = blockIdx.x*256 + threadIdx.x;   // NN1_*KP1_
    if (idx >= NN1_*KP1_) return;
    int n = idx / KP1_, k = idx % KP1_;
    float v = 0.f;
    if (k < 660){
        int u = k / 132, ci = k % 132;
        int co = n / 5, t = n % 5;
        int kk = u - t + 2;
        if (kk >= 0 && kk < 5) v = w[((size_t)co*132 + ci)*5 + kk];
    }
    unsigned short h, l; bsplit(v, h, l);
    Bp[((size_t)n*2 + 0)*KP1_ + k] = h;
    Bp[((size_t)n*2 + 1)*KP1_ + k] = l;
}

// GEMM2 decoder weights -> [n][pl][k = ci*5 + u] bf16 hi/lo (matches H layout)
__global__ __launch_bounds__(256) void k_wexpand2(const float* __restrict__ w, unsigned short* __restrict__ Bp,
                                                  int Cin, int K, int KP, int total){
    int idx = blockIdx.x*256 + threadIdx.x;
    if (idx >= total) return;
    int n = idx / KP, k = idx % KP;
    float v = 0.f;
    if (k < Cin*5){
        int ci = k / 5, u = k % 5;
        int co = n / 5, t = n % 5;
        int kk = u - t + (K-1)/2;
        if (kk >= 0 && kk < K) v = w[((size_t)co*Cin + ci)*K + kk];
    }
    unsigned short h, l; bsplit(v, h, l);
    Bp[((size_t)n*2 + 0)*KP + k] = h;
    Bp[((size_t)n*2 + 1)*KP + k] = l;
}

// codebook prep: norms (fp64+fp32) + bf16 hi/lo planes, K-fragment-interleaved
__global__ __launch_bounds__(256) void k_cbprep(const float* __restrict__ cb,
                                                unsigned short* __restrict__ cbp, double* __restrict__ cnorm,
                                                float* __restrict__ cnf){
    int i = blockIdx.x*256 + threadIdx.x;
    if (i >= Q_*KCB_) return;
    int q = i >> 10, k = i & 1023;
    const float* row = cb + (size_t)i * L_;
    double s = 0.0;
    for (int d = 0; d < L_; ++d){
        float v = row[d];
        s += (double)v * (double)v;
        unsigned short h, l; bsplit(v, h, l);
        int kb = d >> 3, e = d & 7;
        cbp[((((size_t)q*2 + 0)*16 + kb)*1024 + k)*8 + e] = h;
        cbp[((((size_t)q*2 + 1)*16 + kb)*1024 + k)*8 + e] = l;
    }
    cnorm[i] = s;
    cnf[i] = (float)s;
}

__global__ __launch_bounds__(256) void k_buildx(const float* __restrict__ traj, float* __restrict__ x1){
    int i = blockIdx.x*256 + threadIdx.x;
    if (i >= B_*20*TN_) return;
    int b = i / (20*TN_); int r = i % (20*TN_); int ci = r / TN_; int tn = r % TN_;
    int d = ci / 10, kk = ci % 10;
    x1[i] = traj[((size_t)b*2 + d)*T_ + tn*10 + kk];
}

// exact sequential fp32 cumsum-diff, software-pipelined loads
__global__ __launch_bounds__(64) void k_cumsum(float* __restrict__ z1, int rows){
    int row = blockIdx.x*64 + threadIdx.x;
    if (row >= rows) return;
    float* p = z1 + (size_t)row * TN_;
    float run = 0.f;
    float4 v = *(float4*)&p[0];
    int j = 0;
    for (; j < TN_ - 4; j += 4){
        float4 vn = *(float4*)&p[j + 4];
        float prev, o0, o1, o2, o3;
        prev = run; run += v.x; o0 = run - prev;
        prev = run; run += v.y; o1 = run - prev;
        prev = run; run += v.z; o2 = run - prev;
        prev = run; run += v.w; o3 = run - prev;
        *(float4*)&p[j] = make_float4(o0, o1, o2, o3);
        v = vn;
    }
    {
        float prev, o0, o1, o2, o3;
        prev = run; run += v.x; o0 = run - prev;
        prev = run; run += v.y; o1 = run - prev;
        prev = run; run += v.z; o2 = run - prev;
        prev = run; run += v.w; o3 = run - prev;
        *(float4*)&p[j] = make_float4(o0, o1, o2, o3);
    }
}

// upsample z1 (800) -> 8000, token-major bf16 hi/lo planes, zero-padded rows
__global__ __launch_bounds__(256) void k_upT(const float* __restrict__ z1, unsigned short* __restrict__ Zt){
    int idx = blockIdx.x*256 + threadIdx.x;       // over ZROWS_*512
    int lb = blockIdx.y;
    int ci = idx & 511, row = idx >> 9;
    if (row >= ZROWS_) return;
    int t = row - 2;
    float v = 0.f;
    if (t >= 0 && t < T_){
        const float* zr = z1 + (size_t)lb*409600 + (size_t)ci*TN_;
        float s = fmaxf(0.5f*(float)t - 0.25f, 0.f);
        int i0 = (int)s;
        float f = s - (float)i0;
        int i1 = min(i0 + 1, T_/2 - 1);
        v = zr[i0/5]*(1.f - f) + zr[i1/5]*f;
    }
    unsigned short h, l; bsplit(v, h, l);
    unsigned short* dst = Zt + (size_t)lb*((size_t)ZROWS_*ZROWU_) + (size_t)row*ZROWU_;
    dst[ci] = h;
    dst[512 + ci] = l;
}

// zero halo rows of z2t: rows 0..2 and 8003..8071
__global__ __launch_bounds__(256) void k_zpad2(unsigned short* __restrict__ z2t, int bc){
    int idx = blockIdx.x*256 + threadIdx.x;     // uint4 units, 9216 per lb
    int lb = idx / 9216;
    if (lb >= bc) return;
    int r = idx % 9216;
    int rid = r >> 7, off = r & 127;
    int row = (rid < 3) ? rid : (8000 + rid);
    uint4 z = make_uint4(0,0,0,0);
    *(uint4*)&z2t[(size_t)lb*(Z2ROWS_*Z2ROWU_) + (size_t)row*Z2ROWU_ + (size_t)off*8] = z;
}

// ---------------- generic tiled conv1d fp32 (conv1 only) ----------------
template<int K, bool RELU, bool UPS, int TT>
__global__ __launch_bounds__(256) void k_conv(const float* __restrict__ in, const float* __restrict__ wT,
                                              const float* __restrict__ bias, float* __restrict__ out,
                                              int Cin, int CO, int T){
    constexpr int P   = (K-1)/2;
    constexpr int TIN = TT + K - 1;
    constexpr int TINP = ((TIN + 3) & ~3) + 4;
    constexpr int NG  = TT/64;
    __shared__ float inS[8][TINP];
    __shared__ float wS[8][K][128];
    int b  = blockIdx.z;
    int t0 = blockIdx.x * TT;
    int co0 = blockIdx.y * 128;
    int tid = threadIdx.x, tx = tid & 15, ty = tid >> 4;
    v2f acc[8][NG*2];
    #pragma unroll
    for (int i = 0; i < 8; ++i)
        #pragma unroll
        for (int j = 0; j < NG*2; ++j) acc[i][j] = (v2f){0.f, 0.f};

    const int inrow = UPS ? (T/10) : T;
    const int i1cap = UPS ? (T/2 - 1) : 0;
    const float* inB = in + (size_t)b * Cin * inrow;

    for (int ci0 = 0; ci0 < Cin; ci0 += 8){
        __syncthreads();
        for (int idx = tid; idx < 8*TIN; idx += 256){
            int ci = idx / TIN, tt = idx % TIN;
            int t = t0 + tt - P;
            int cig = ci0 + ci;
            float v = 0.f;
            if (cig < Cin && t >= 0 && t < T){
                const float* row = inB + (size_t)cig * inrow;
                if (UPS){
                    float s = fmaxf(0.5f*(float)t - 0.25f, 0.f);
                    int i0 = (int)s;
                    float f = s - (float)i0;
                    int i1 = min(i0 + 1, i1cap);
                    v = row[i0/5]*(1.f - f) + row[i1/5]*f;
                } else {
                    v = row[t];
                }
            }
            inS[ci][tt] = v;
        }
        for (int idx = tid; idx < 8*K*32; idx += 256){
            int ci = idx / (K*32);
            int rr = idx % (K*32);
            int k = rr / 32, co4 = (rr & 31)*4;
            int cig = ci0 + ci;
            float4 v = make_float4(0.f,0.f,0.f,0.f);
            if (cig < Cin) v = *(const float4*)&wT[((size_t)cig*K + k)*CO + co0 + co4];
            *(float4*)&wS[ci][k][co4] = v;
        }
        __syncthreads();
        #pragma unroll 1
        for (int ci = 0; ci < 8; ++ci){
            float win[NG][8];
            #pragma unroll
            for (int g = 0; g < NG; ++g){
                float4 a0 = *(const float4*)&inS[ci][g*64 + tx*4];
                float4 a1 = *(const float4*)&inS[ci][g*64 + tx*4 + 4];
                win[g][0]=a0.x; win[g][1]=a0.y; win[g][2]=a0.z; win[g][3]=a0.w;
                win[g][4]=a1.x; win[g][5]=a1.y; win[g][6]=a1.z; win[g][7]=a1.w;
            }
            #pragma unroll
            for (int k = 0; k < K; ++k){
                v2f a2[NG*2];
                #pragma unroll
                for (int g = 0; g < NG; ++g){
                    a2[g*2+0] = (v2f){win[g][k+0], win[g][k+1]};
                    a2[g*2+1] = (v2f){win[g][k+2], win[g][k+3]};
                }
                float4 w0 = *(const float4*)&wS[ci][k][ty*4];
                float4 w1 = *(const float4*)&wS[ci][k][64 + ty*4];
                float w[8] = {w0.x,w0.y,w0.z,w0.w, w1.x,w1.y,w1.z,w1.w};
                #pragma unroll
                for (int i = 0; i < 8; ++i){
                    v2f wv = (v2f){w[i], w[i]};
                    #pragma unroll
                    for (int j = 0; j < NG*2; ++j)
                        acc[i][j] = PKFMA(wv, a2[j], acc[i][j]);
                }
            }
        }
    }
    #pragma unroll
    for (int i = 0; i < 8; ++i){
        int co = co0 + (i < 4 ? ty*4 + i : 64 + ty*4 + (i-4));
        float bv = bias[co];
        #pragma unroll
        for (int g = 0; g < NG; ++g){
            int t = t0 + g*64 + tx*4;
            if (t >= T) continue;
            float v0 = acc[i][g*2+0].x + bv;
            float v1 = acc[i][g*2+0].y + bv;
            float v2 = acc[i][g*2+1].x + bv;
            float v3 = acc[i][g*2+1].y + bv;
            if (RELU){ v0=fmaxf(v0,0.f); v1=fmaxf(v1,0.f); v2=fmaxf(v2,0.f); v3=fmaxf(v3,0.f); }
            *(float4*)&out[((size_t)b*CO + co)*T + t] = make_float4(v0,v1,v2,v3);
        }
    }
}

// ---------------- conv2a via MFMA bf16x3, u-shift staging, bank-conflict-free stride 40 ----------------
__global__ __launch_bounds__(256) void k_mconv2a(const unsigned short* __restrict__ Zt,
                                                 const unsigned short* __restrict__ Wp,
                                                 const float* __restrict__ bias,
                                                 unsigned short* __restrict__ z2t){
    __shared__ unsigned short SH[20800];   // 41600 B; ZL[pl][132][40] at 0, WL[pl][128][40] at 10560
    int lb = blockIdx.z;
    int t0 = blockIdx.x * 128;
    int co0 = blockIdx.y * 128;
    int tid = threadIdx.x;
    int lane = tid & 63, wid = tid >> 6;
    int wr = wid >> 1, wc = wid & 1;
    int lr = lane & 15, lg = lane >> 4;
    const unsigned short* Zb = Zt + (size_t)lb*((size_t)ZROWS_*ZROWU_);   // row index = t + 2
    f32x4 acc[4][4];
    #pragma unroll
    for (int i = 0; i < 4; ++i)
        #pragma unroll
        for (int j = 0; j < 4; ++j) acc[i][j] = (f32x4){0.f,0.f,0.f,0.f};

    for (int ci0 = 0; ci0 < 512; ci0 += 32){
        __syncthreads();
        for (int idx = tid; idx < 1056; idx += 256){
            int row = idx >> 3, rem = idx & 7, pl = rem >> 2, qo = rem & 3;
            *(uint4*)&SH[pl*5280 + row*40 + qo*8] =
                *(const uint4*)&Zb[(size_t)(t0 + row)*ZROWU_ + (size_t)pl*512 + ci0 + qo*8];
        }
        for (int u = 0; u < 5; ++u){
            if (u) __syncthreads();
            #pragma unroll
            for (int p = 0; p < 4; ++p){
                int idx = p*256 + tid;
                int n = idx >> 3, rem = idx & 7, pl = rem >> 2, qo = rem & 3;
                *(uint4*)&SH[10560 + pl*5120 + n*40 + qo*8] =
                    *(const uint4*)&Wp[((size_t)(co0+n)*2 + pl)*2560 + u*512 + ci0 + qo*8];
            }
            __syncthreads();
            s16x8 w[2][4], z[2][4];
            #pragma unroll
            for (int pl = 0; pl < 2; ++pl)
                #pragma unroll
                for (int mi = 0; mi < 4; ++mi)
                    w[pl][mi] = *(const s16x8*)&SH[10560 + pl*5120 + (wr*64 + mi*16 + lr)*40 + lg*8];
            #pragma unroll
            for (int pl = 0; pl < 2; ++pl)
                #pragma unroll
                for (int ni = 0; ni < 4; ++ni)
                    z[pl][ni] = *(const s16x8*)&SH[pl*5280 + (wc*64 + ni*16 + lr + u)*40 + lg*8];
            #pragma unroll
            for (int mi = 0; mi < 4; ++mi)
                #pragma unroll
                for (int ni = 0; ni < 4; ++ni){
                    f32x4 c = acc[mi][ni];
                    c = MFMA16(w[0][mi], z[0][ni], c);
                    c = MFMA16(w[0][mi], z[1][ni], c);
                    c = MFMA16(w[1][mi], z[0][ni], c);
                    acc[mi][ni] = c;
                }
        }
    }
    // epilogue: relu+bias, bf16-split, LDS-transpose to [t][co], write token-major planes
    unsigned short* Zo = z2t + (size_t)lb*(Z2ROWS_*Z2ROWU_);
    #pragma unroll
    for (int pl = 0; pl < 2; ++pl){
        __syncthreads();
        #pragma unroll
        for (int mi = 0; mi < 4; ++mi){
            int cb = wr*64 + mi*16 + lg*4;
            #pragma unroll
            for (int ni = 0; ni < 4; ++ni){
                int tl = wc*64 + ni*16 + lr;
                #pragma unroll
                for (int r = 0; r < 4; ++r){
                    float v = fmaxf(acc[mi][ni][r] + bias[co0 + cb + r], 0.f);
                    unsigned short h, l; bsplit(v, h, l);
                    SH[tl*136 + cb + r] = pl ? l : h;
                }
            }
        }
        __syncthreads();
        int tl = tid >> 1, half = tid & 1;
        if (t0 + tl < T_){
            uint4* dst = (uint4*)&Zo[((size_t)(t0 + tl + 3))*Z2ROWU_ + (size_t)pl*512 + co0 + half*64];
            const uint4* src = (const uint4*)&SH[tl*136 + half*64];
            #pragma unroll
            for (int e = 0; e < 8; ++e) dst[e] = src[e];
        }
    }
}

// ---------------- conv2b via MFMA bf16x3, TT=64, bank-conflict-free stride 40 ----------------
__global__ __launch_bounds__(256) void k_mconv2b(const unsigned short* __restrict__ Z2,
                                                 const unsigned short* __restrict__ Wp,
                                                 const float* __restrict__ bias,
                                                 float* __restrict__ ze){
    __shared__ unsigned short SH[15840];   // 31680 B; ZL[pl][70][40] at 0, WL[pl][128][40] at 5600
    int lb = blockIdx.y;
    int t0 = blockIdx.x * 64;
    int tid = threadIdx.x;
    int lane = tid & 63, wid = tid >> 6;
    int lr = lane & 15, lg = lane >> 4;
    const unsigned short* Zb = Z2 + (size_t)lb*(Z2ROWS_*Z2ROWU_);
    f32x4 acc[2][4];
    #pragma unroll
    for (int i = 0; i < 2; ++i)
        #pragma unroll
        for (int j = 0; j < 4; ++j) acc[i][j] = (f32x4){0.f,0.f,0.f,0.f};

    for (int ci0 = 0; ci0 < 512; ci0 += 32){
        __syncthreads();
        // stage Z2 tile rows t0 .. t0+69 (z2t row = t + 3; taps u=0..6 read m+u)
        for (int idx = tid; idx < 560; idx += 256){
            int row = idx >> 3, rem = idx & 7, pl = rem >> 2, qo = rem & 3;
            *(uint4*)&SH[pl*2800 + row*40 + qo*8] =
                *(const uint4*)&Zb[(size_t)(t0 + row)*Z2ROWU_ + (size_t)pl*512 + ci0 + qo*8];
        }
        for (int u = 0; u < 7; ++u){
            if (u) __syncthreads();
            #pragma unroll
            for (int p = 0; p < 4; ++p){
                int idx = p*256 + tid;
                int n = idx >> 3, rem = idx & 7, pl = rem >> 2, qo = rem & 3;
                *(uint4*)&SH[5600 + pl*5120 + n*40 + qo*8] =
                    *(const uint4*)&Wp[((size_t)n*2 + pl)*3584 + u*512 + ci0 + qo*8];
            }
            __syncthreads();
            s16x8 w[2][2], z[2][4];
            #pragma unroll
            for (int pl = 0; pl < 2; ++pl)
                #pragma unroll
                for (int mi = 0; mi < 2; ++mi)
                    w[pl][mi] = *(const s16x8*)&SH[5600 + pl*5120 + (wid*32 + mi*16 + lr)*40 + lg*8];
            #pragma unroll
            for (int pl = 0; pl < 2; ++pl)
                #pragma unroll
                for (int ni = 0; ni < 4; ++ni)
                    z[pl][ni] = *(const s16x8*)&SH[pl*2800 + (ni*16 + lr + u)*40 + lg*8];
            #pragma unroll
            for (int mi = 0; mi < 2; ++mi)
                #pragma unroll
                for (int ni = 0; ni < 4; ++ni){
                    f32x4 c = acc[mi][ni];
                    c = MFMA16(w[0][mi], z[0][ni], c);
                    c = MFMA16(w[0][mi], z[1][ni], c);
                    c = MFMA16(w[1][mi], z[0][ni], c);
                    acc[mi][ni] = c;
                }
        }
    }
    #pragma unroll
    for (int mi = 0; mi < 2; ++mi){
        int cb = wid*32 + mi*16 + lg*4;
        float4 bv = *(const float4*)&bias[cb];
        #pragma unroll
        for (int ni = 0; ni < 4; ++ni){
            int t = t0 + ni*16 + lr;
            float4 o;
            o.x = acc[mi][ni][0] + bv.x;
            o.y = acc[mi][ni][1] + bv.y;
            o.z = acc[mi][ni][2] + bv.z;
            o.w = acc[mi][ni][3] + bv.w;
            *(float4*)&ze[((size_t)lb*T_ + t)*L_ + cb] = o;
        }
    }
}

// ---------------- MFMA GEMM1: H = relu(A·B + bias[n/5]), bf16x3 split ----------------
__global__ __launch_bounds__(256) void k_mgemm1(const unsigned short* __restrict__ Ap,
                                                const unsigned short* __restrict__ Bp,
                                                const float* __restrict__ bias,
                                                unsigned short* __restrict__ Hp){
    __shared__ unsigned short AL[2][128][40];
    __shared__ unsigned short BL[2][128][40];
    int m0 = blockIdx.x * 128, n0 = blockIdx.y * 128;
    int tid = threadIdx.x;
    int lane = tid & 63, wid = tid >> 6;
    int wr = wid >> 1, wc = wid & 1;
    int lr = lane & 15, lg = lane >> 4;
    f32x4 acc[4][4];
    #pragma unroll
    for (int i = 0; i < 4; ++i)
        #pragma unroll
        for (int j = 0; j < 4; ++j) acc[i][j] = (f32x4){0.f,0.f,0.f,0.f};

    for (int kb = 0; kb < KP1_; kb += 32){
        __syncthreads();
        #pragma unroll
        for (int p = 0; p < 4; ++p){
            int slot = p*256 + tid;
            int m = slot >> 3, pl = (slot >> 2) & 1, q = slot & 3;
            uint4 v = *(const uint4*)&Ap[((size_t)(m0+m)*2 + pl)*KP1_ + kb + q*8];
            *(uint4*)&AL[pl][m][q*8] = v;
        }
        #pragma unroll
        for (int p = 0; p < 4; ++p){
            int slot = p*256 + tid;
            int n = slot >> 3, pl = (slot >> 2) & 1, q = slot & 3;
            uint4 v = *(const uint4*)&Bp[((size_t)(n0+n)*2 + pl)*KP1_ + kb + q*8];
            *(uint4*)&BL[pl][n][q*8] = v;
        }
        __syncthreads();
        s16x8 a[2][4], b[2][4];
        #pragma unroll
        for (int pl = 0; pl < 2; ++pl)
            #pragma unroll
            for (int mi = 0; mi < 4; ++mi)
                a[pl][mi] = *(const s16x8*)&AL[pl][wr*64 + mi*16 + lr][lg*8];
        #pragma unroll
        for (int pl = 0; pl < 2; ++pl)
            #pragma unroll
            for (int ni = 0; ni < 4; ++ni)
                b[pl][ni] = *(const s16x8*)&BL[pl][wc*64 + ni*16 + lr][lg*8];
        #pragma unroll
        for (int mi = 0; mi < 4; ++mi)
            #pragma unroll
            for (int ni = 0; ni < 4; ++ni){
                f32x4 c = acc[mi][ni];
                c = MFMA16(a[0][mi], b[0][ni], c);
                c = MFMA16(a[0][mi], b[1][ni], c);
                c = MFMA16(a[1][mi], b[0][ni], c);
                acc[mi][ni] = c;
            }
    }
    #pragma unroll
    for (int mi = 0; mi < 4; ++mi){
        int mbase = m0 + wr*64 + mi*16 + lg*4;
        #pragma unroll
        for (int ni = 0; ni < 4; ++ni){
            int n = n0 + wc*64 + ni*16 + lr;
            float bv = bias[n/5];
            #pragma unroll
            for (int r = 0; r < 4; ++r){
                float v = fmaxf(acc[mi][ni][r] + bv, 0.f);
                unsigned short h, l; bsplit(v, h, l);
                size_t m = (size_t)(mbase + r);
                Hp[(m*2 + 0)*NN1_ + n] = h;
                Hp[(m*2 + 1)*NN1_ + n] = l;
            }
        }
    }
}

// ---------------- MFMA GEMM2 + fused recon loss, bf16x3 split ----------------
__global__ __launch_bounds__(256) void k_mgemm2rec(const unsigned short* __restrict__ Ap,
                                                   const unsigned short* __restrict__ Bp,
                                                   const float* __restrict__ bias,
                                                   const float* __restrict__ zeq, float* __restrict__ scal,
                                                   int M, int m0g){
    __shared__ unsigned short AL[2][128][40];
    __shared__ unsigned short BL[2][128][40];
    int m0 = blockIdx.x * 128, n0 = blockIdx.y * 128;
    int tid = threadIdx.x;
    int lane = tid & 63, wid = tid >> 6;
    int wr = wid >> 1, wc = wid & 1;
    int lr = lane & 15, lg = lane >> 4;
    f32x4 acc[4][4];
    #pragma unroll
    for (int i = 0; i < 4; ++i)
        #pragma unroll
        for (int j = 0; j < 4; ++j) acc[i][j] = (f32x4){0.f,0.f,0.f,0.f};

    for (int kb = 0; kb < KP2_; kb += 32){
        __syncthreads();
        #pragma unroll
        for (int p = 0; p < 4; ++p){
            int slot = p*256 + tid;
            int m = slot >> 3, pl = (slot >> 2) & 1, q = slot & 3;
            uint4 v = *(const uint4*)&Ap[((size_t)(m0+m)*2 + pl)*KP2_ + kb + q*8];
            *(uint4*)&AL[pl][m][q*8] = v;
        }
        #pragma unroll
        for (int p = 0; p < 4; ++p){
            int slot = p*256 + tid;
            int n = slot >> 3, pl = (slot >> 2) & 1, q = slot & 3;
            uint4 v = *(const uint4*)&Bp[((size_t)(n0+n)*2 + pl)*KP2_ + kb + q*8];
            *(uint4*)&BL[pl][n][q*8] = v;
        }
        __syncthreads();
        s16x8 a[2][4], b[2][4];
        #pragma unroll
        for (int pl = 0; pl < 2; ++pl)
            #pragma unroll
            for (int mi = 0; mi < 4; ++mi)
                a[pl][mi] = *(const s16x8*)&AL[pl][wr*64 + mi*16 + lr][lg*8];
        #pragma unroll
        for (int pl = 0; pl < 2; ++pl)
            #pragma unroll
            for (int ni = 0; ni < 4; ++ni)
                b[pl][ni] = *(const s16x8*)&BL[pl][wc*64 + ni*16 + lr][lg*8];
        #pragma unroll
        for (int mi = 0; mi < 4; ++mi)
            #pragma unroll
            for (int ni = 0; ni < 4; ++ni){
                f32x4 c = acc[mi][ni];
                c = MFMA16(a[0][mi], b[0][ni], c);
                c = MFMA16(a[0][mi], b[1][ni], c);
                c = MFMA16(a[1][mi], b[0][ni], c);
                acc[mi][ni] = c;
            }
    }
    float lsum = 0.f;
    #pragma unroll
    for (int mi = 0; mi < 4; ++mi){
        #pragma unroll
        for (int r = 0; r < 4; ++r){
            int ml = wr*64 + mi*16 + lg*4 + r;
            int mlg = m0 + ml;
            if (mlg >= M) continue;
            int gm = m0g + mlg;
            int b = gm / COUNT_, c = gm % COUNT_;
            const float* tgtB = zeq + ((size_t)b*T_ + (size_t)(c+1)*5) * L_;
            #pragma unroll
            for (int ni = 0; ni < 4; ++ni){
                int n = n0 + wc*64 + ni*16 + lr;
                int co = n / 5, t = n % 5;
                float v = acc[mi][ni][r] + bias[co];
                float d = v - tgtB[(size_t)t*L_ + co];
                lsum += d*d;
            }
        }
    }
    lsum = wred(lsum);
    if (lane == 0) atomicAdd(&scal[1024 + ((blockIdx.x*5 + blockIdx.y) & 255)], lsum);
}

// ---------------- VQ phase v14: split screen/rotate kernels ----------------
__global__ __launch_bounds__(256) void k_vqcopy(const float* __restrict__ src, float* __restrict__ dst){
    size_t i = ((size_t)blockIdx.x*256 + threadIdx.x)*4;
    *(float4*)&dst[i] = *(const float4*)&src[i];
}

// screening: bf16x3 MFMA distances + per-token top-2 -> top2G (no rf LDS, no fp64)
__global__ __launch_bounds__(256, 2) void k_vqscreen(const float* __restrict__ resid,
                                                     const unsigned short* __restrict__ cbp,
                                                     const float* __restrict__ cnf,
                                                     float* __restrict__ top2, int q){
    __shared__ unsigned short rb[2][64][136];  // 34816 B residual bf16 hi/lo planes
    __shared__ float mvS[4][64][2];
    __shared__ int   miS[4][64][2];
    int tok0 = blockIdx.x * 64;
    int tid = threadIdx.x;
    int lane = tid & 63, wv = tid >> 6;
    int lr = lane & 15, lg = lane >> 4;
    int tok = tid >> 2, sub = tid & 3, dbase = sub*32;
    // phase 0: residual -> bf16 hi/lo planes (own slice, from global)
    {
        const float* zp = &resid[((size_t)(tok0 + tok))*L_ + dbase];
        #pragma unroll
        for (int j = 0; j < 4; ++j){
            float4 va = *(const float4*)&zp[j*8];
            float4 vb = *(const float4*)&zp[j*8 + 4];
            float rv[8] = {va.x,va.y,va.z,va.w, vb.x,vb.y,vb.z,vb.w};
            unsigned hp[4], lp[4];
            #pragma unroll
            for (int e = 0; e < 4; ++e){
                unsigned short h0,l0,h1,l1;
                bsplit(rv[e*2+0], h0, l0);
                bsplit(rv[e*2+1], h1, l1);
                hp[e] = (unsigned)h0 | ((unsigned)h1 << 16);
                lp[e] = (unsigned)l0 | ((unsigned)l1 << 16);
            }
            *(uint4*)&rb[0][tok][dbase + j*8] = make_uint4(hp[0],hp[1],hp[2],hp[3]);
            *(uint4*)&rb[1][tok][dbase + j*8] = make_uint4(lp[0],lp[1],lp[2],lp[3]);
        }
    }
    __syncthreads();
    // phase 1: screening GEMM; wave wv owns codes [wv*256, +256), 8 chunks of 32
    const unsigned short* cq = cbp + (size_t)q*(2*16*1024*8);
    const float* cnq = cnf + (size_t)q*KCB_;
    int code0w = wv*256;
    float m1[4], m2[4]; int i1[4], i2[4];
    #pragma unroll
    for (int t = 0; t < 4; ++t){ m1[t]=3.4e38f; m2[t]=3.4e38f; i1[t]=0x7fffffff; i2[t]=0x7fffffff; }
    for (int ch = 0; ch < 8; ++ch){
        f32x4 acc[2][4];
        #pragma unroll
        for (int i = 0; i < 2; ++i)
            #pragma unroll
            for (int j = 0; j < 4; ++j) acc[i][j] = (f32x4){0.f,0.f,0.f,0.f};
        #pragma unroll
        for (int ks = 0; ks < 4; ++ks){
            s16x8 b0[4], b1[4];
            #pragma unroll
            for (int tf = 0; tf < 4; ++tf){
                b0[tf] = *(const s16x8*)&rb[0][tf*16 + lr][ks*32 + lg*8];
                b1[tf] = *(const s16x8*)&rb[1][tf*16 + lr][ks*32 + lg*8];
            }
            #pragma unroll
            for (int mi = 0; mi < 2; ++mi){
                s16x8 a0 = *(const s16x8*)&cq[((size_t)(0*16 + ks*4 + lg)*1024
                                               + code0w + ch*32 + mi*16 + lr)*8];
                s16x8 a1 = *(const s16x8*)&cq[((size_t)(1*16 + ks*4 + lg)*1024
                                               + code0w + ch*32 + mi*16 + lr)*8];
                #pragma unroll
                for (int tf = 0; tf < 4; ++tf){
                    f32x4 c = acc[mi][tf];
                    c = MFMA16(a0, b0[tf], c);
                    c = MFMA16(a0, b1[tf], c);
                    c = MFMA16(a1, b0[tf], c);
                    acc[mi][tf] = c;
                }
            }
        }
        // selection: code = code0w + ch*32 + mi*16 + lg*4 + rr (monotone per lane)
        #pragma unroll
        for (int mi = 0; mi < 2; ++mi){
            float4 cn4 = *(const float4*)&cnq[code0w + ch*32 + mi*16 + lg*4];
            float cnv[4] = {cn4.x, cn4.y, cn4.z, cn4.w};
            #pragma unroll
            for (int tf = 0; tf < 4; ++tf)
                #pragma unroll
                for (int rr = 0; rr < 4; ++rr){
                    float sc = cnv[rr] - 2.f*acc[mi][tf][rr];
                    int code = code0w + ch*32 + mi*16 + lg*4 + rr;
                    bool c1 = sc < m1[tf];
                    bool c2 = sc < m2[tf];
                    if (c1){ m2[tf]=m1[tf]; i2[tf]=i1[tf]; m1[tf]=sc; i1[tf]=code; }
                    else if (c2){ m2[tf]=sc; i2[tf]=code; }
                }
        }
    }
    // cross-lane merge over lg groups (xor 16, 32)
    #pragma unroll
    for (int tf = 0; tf < 4; ++tf){
        float a1 = m1[tf], a2 = m2[tf]; int ai1 = i1[tf], ai2 = i2[tf];
        #pragma unroll
        for (int m = 16; m <= 32; m <<= 1){
            float o1 = __shfl_xor(a1, m), o2 = __shfl_xor(a2, m);
            int oi1 = __shfl_xor(ai1, m), oi2 = __shfl_xor(ai2, m);
            bool sw = (o1 < a1) || (o1 == a1 && oi1 < ai1);
            float w1 = sw ? o1 : a1;  int wi1 = sw ? oi1 : ai1;
            float l1 = sw ? a1 : o1;  int li1 = sw ? ai1 : oi1;
            float w2 = sw ? o2 : a2;  int wi2 = sw ? oi2 : ai2;
            bool s2 = (l1 < w2) || (l1 == w2 && li1 < wi2);
            a1 = w1; ai1 = wi1;
            a2 = s2 ? l1 : w2; ai2 = s2 ? li1 : wi2;
        }
        if (lg == 0){
            mvS[wv][tf*16 + lr][0] = a1; mvS[wv][tf*16 + lr][1] = a2;
            miS[wv][tf*16 + lr][0] = ai1; miS[wv][tf*16 + lr][1] = ai2;
        }
    }
    __syncthreads();
    // final merge across 4 waves; one writer per token
    if (tid < 64){
        float a1 = mvS[0][tid][0], a2 = mvS[0][tid][1];
        int ai1 = miS[0][tid][0], ai2 = miS[0][tid][1];
        #pragma unroll
        for (int w = 1; w < 4; ++w){
            float o1 = mvS[w][tid][0], o2 = mvS[w][tid][1];
            int oi1 = miS[w][tid][0], oi2 = miS[w][tid][1];
            bool sw = (o1 < a1) || (o1 == a1 && oi1 < ai1);
            float w1 = sw ? o1 : a1;  int wi1 = sw ? oi1 : ai1;
            float l1 = sw ? a1 : o1;  int li1 = sw ? ai1 : oi1;
            float w2 = sw ? o2 : a2;  int wi2 = sw ? oi2 : ai2;
            bool s2 = (l1 < w2) || (l1 == w2 && li1 < wi2);
            a1 = w1; ai1 = wi1;
            a2 = s2 ? l1 : w2; ai2 = s2 ? li1 : wi2;
        }
        float* t2 = &top2[((size_t)(tok0 + tid))*4];
        t2[0] = a1; t2[1] = a2;
        ((int*)t2)[2] = ai1; ((int*)t2)[3] = ai2;
    }
}

// rotation: fp64 recheck + rotate-to + commit loss + codes; residual in registers
__global__ __launch_bounds__(256, 2) void k_vqrot(float* __restrict__ ze, float* __restrict__ resid,
                                                  const float* __restrict__ top2,
                                                  const double* __restrict__ cnorm,
                                                  const float* __restrict__ cb,
                                                  int* __restrict__ codes, float* __restrict__ scal,
                                                  int q, int last){
    int tok0 = blockIdx.x * 64;
    int tid = threadIdx.x;
    int tok = tid >> 2, sub = tid & 3, dbase = sub*32;
    float r[32];
    {
        const float* zp = &resid[((size_t)(tok0 + tok))*L_ + dbase];
        #pragma unroll
        for (int h = 0; h < 8; ++h){
            float4 v = *(const float4*)&zp[h*4];
            r[h*4+0]=v.x; r[h*4+1]=v.y; r[h*4+2]=v.z; r[h*4+3]=v.w;
        }
    }
    const float* t2 = &top2[((size_t)(tok0 + tok))*4];
    float a1 = t2[0], a2 = t2[1];
    int id = ((const int*)t2)[2];
    int idb = (a2 - a1 < 0.1f) ? ((const int*)t2)[3] : -1;

    const float* cbq  = cb + (size_t)q*KCB_*L_;
    const double* cnq64 = cnorm + (size_t)q*KCB_;
    if (idb >= 0){
        const float* c1p = cbq + (size_t)id * L_ + dbase;
        const float* c2p = cbq + (size_t)idb * L_ + dbase;
        double p1 = 0.0, p2 = 0.0;
        #pragma unroll
        for (int h = 0; h < 8; ++h){
            float4 a4 = *(const float4*)&c1p[h*4];
            float4 b4 = *(const float4*)&c2p[h*4];
            float ca[4] = {a4.x,a4.y,a4.z,a4.w};
            float cbv[4] = {b4.x,b4.y,b4.z,b4.w};
            #pragma unroll
            for (int e = 0; e < 4; ++e){
                double rv = (double)r[h*4 + e];
                p1 = fma(rv, (double)ca[e], p1);
                p2 = fma(rv, (double)cbv[e], p2);
            }
        }
        p1 = qred(p1); p2 = qred(p2);
        double d1 = cnq64[id]  - 2.0*p1;
        double d2 = cnq64[idb] - 2.0*p2;
        if (d2 < d1 || (d2 == d1 && idb < id)) id = idb;
    }
    if (sub == 0) codes[((size_t)(tok0 + tok))*Q_ + q] = id;

    const float* cp = cbq + (size_t)id * L_ + dbase;
    double srr = 0.0, scc = 0.0, src = 0.0;
    #pragma unroll
    for (int h = 0; h < 8; ++h){
        float4 c4 = *(const float4*)&cp[h*4];
        float cvs[4] = {c4.x,c4.y,c4.z,c4.w};
        #pragma unroll
        for (int e = 0; e < 4; ++e){
            double rd = (double)r[h*4 + e];
            double cd = (double)cvs[e];
            srr = fma(rd, rd, srr);
            scc = fma(cd, cd, scc);
            src = fma(rd, cd, src);
        }
    }
    srr = qred(srr); scc = qred(scc); src = qred(src);
    double ns = sqrt(srr), nt = sqrt(scc);
    double insp = 1.0/(ns + EPSF), intp = 1.0/(nt + EPSF);
    double sn2 = srr*insp*insp + 2.0*src*insp*intp + scc*intp*intp;
    double isn = 1.0/(sqrt(sn2) + EPSF);
    double ew = (srr*insp + src*intp)*isn;
    double eu = srr*insp;
    double scale = nt*insp;
    double clp = 0.0;
    #pragma unroll
    for (int h = 0; h < 8; ++h){
        float4 c4 = *(const float4*)&cp[h*4];
        float cvs[4] = {c4.x,c4.y,c4.z,c4.w};
        #pragma unroll
        for (int e = 0; e < 4; ++e){
            float rf32 = r[h*4 + e];
            double rv = (double)rf32, cd = (double)cvs[e];
            double wd = (rv*insp + cd*intp)*isn;
            double qd = cd*intp;
            float qr = (float)((rv - 2.0*ew*wd + 2.0*eu*qd)*scale);
            r[h*4 + e] = rf32 - qr;
            float dd = cvs[e] - rf32;
            clp += (double)(dd*dd);
        }
    }
    clp = qred(clp);
    double cl = (sub == 0) ? clp : 0.0;
    cl = wredd(cl);
    if ((tid & 63) == 0) atomicAdd(&scal[q*256 + (blockIdx.x & 255)], (float)cl);

    if (!last){
        float* rp = &resid[((size_t)(tok0 + tok))*L_ + dbase];
        #pragma unroll
        for (int h = 0; h < 8; ++h)
            *(float4*)&rp[h*4] = make_float4(r[h*4+0], r[h*4+1], r[h*4+2], r[h*4+3]);
    } else {
        float* zw = &ze[((size_t)(tok0 + tok))*L_ + dbase];
        #pragma unroll
        for (int h = 0; h < 8; ++h){
            float4 o = *(float4*)&zw[h*4];
            o.x -= r[h*4+0];
            o.y -= r[h*4+1];
            o.z -= r[h*4+2];
            o.w -= r[h*4+3];
            *(float4*)&zw[h*4] = o;
        }
    }
}

// ---------------- losses / decoder glue ----------------
__global__ __launch_bounds__(256) void k_smooth(const int* __restrict__ codes, float* __restrict__ scal){
    int i = blockIdx.x*256 + threadIdx.x;
    float v = 0.f;
    if (i < B_*(T_-1)){
        int b = i / (T_-1), t = i % (T_-1);
        int c0 = codes[((size_t)b*T_ + t)*Q_];
        int c1 = codes[((size_t)b*T_ + t + 1)*Q_];
        v = (c0 != c1) ? 1.f : 0.f;
    }
    v = wred(v);
    if ((threadIdx.x & 63) == 0) atomicAdd(&scal[1280 + (blockIdx.x & 255)], v);
}

// build A1 hi/lo bf16 planes [m][pl][k' = u*132 + ci]; coalesced zeq reads + A1 writes
__global__ __launch_bounds__(256) void k_builda1b(const float* __restrict__ zeq,
                                                  const int* __restrict__ codes, unsigned short* __restrict__ A1,
                                                  int m0, int M, int Mpad){
    int i = blockIdx.x*256 + threadIdx.x;
    if (i >= Mpad*KP1_) return;
    int ml = i / KP1_, k = i % KP1_;
    float v = 0.f;
    if (ml < M && k < 660){
        int u = k / 132, ci = k % 132;
        int gm = m0 + ml;
        int b = gm / COUNT_, c = gm % COUNT_;
        int t = c*5 + u;
        if (ci < L_) v = zeq[((size_t)b*T_ + t)*L_ + ci];
        else         v = (float)codes[((size_t)b*T_ + t)*Q_ + (ci - L_)];
    }
    unsigned short h, l; bsplit(v, h, l);
    A1[((size_t)ml*2 + 0)*KP1_ + k] = h;
    A1[((size_t)ml*2 + 1)*KP1_ + k] = l;
}

__global__ __launch_bounds__(256) void k_codesout(const int* __restrict__ codes, float* __restrict__ out){
    int i = blockIdx.x*256 + threadIdx.x;
    if (i < NTOK_*Q_) out[i] = (float)codes[i];
}

__global__ __launch_bounds__(64) void k_final(const float* __restrict__ scal, float* __restrict__ out){
    if (threadIdx.x != 0) return;
    double s[4] = {0,0,0,0};
    double rec = 0, sm = 0;
    for (int i = 0; i < 256; ++i){
        s[0] += scal[i]; s[1] += scal[256+i]; s[2] += scal[512+i]; s[3] += scal[768+i];
        rec += scal[1024+i]; sm += scal[1280+i];
    }
    double denom = 16384000.0;
    double vq = (s[0]/denom + s[1]/denom + s[2]/denom + s[3]/denom) / 4.0;
    double recon = rec / 16373760.0;
    double smooth = sm / 127984.0;
    double loss = recon + vq + 0.1*smooth;
    out[512000] = (float)loss;
    out[512001] = (float)recon;
    out[512002] = (float)vq;
    out[512003] = (float)smooth;
}

// ---------------- launch ----------------
extern "C" void kernel_launch(void* const* d_in, const int* in_sizes, int n_in,
                              void* d_out, int out_size, void* d_ws, size_t ws_size,
                              hipStream_t stream) {
    const float* traj = (const float*)d_in[0];
    const float* e1w  = (const float*)d_in[2];
    const float* e1b  = (const float*)d_in[3];
    const float* e2aw = (const float*)d_in[4];
    const float* e2ab = (const float*)d_in[5];
    const float* e2bw = (const float*)d_in[6];
    const float* e2bb = (const float*)d_in[7];
    const float* d1w  = (const float*)d_in[8];
    const float* d1b  = (const float*)d_in[9];
    const float* d2w  = (const float*)d_in[10];
    const float* d2b  = (const float*)d_in[11];
    const float* cbks = (const float*)d_in[12];
    float* out = (float*)d_out;
    float* ws  = (float*)d_ws;
    int* codes_i = (int*)(ws + OFF_CODES);
    double* cnormd = (double*)(ws + OFF_CNORM);

    size_t wsf = ws_size / 4;
    size_t avail = (wsf > OFF_SCR) ? (wsf - OFF_SCR) : 0;
    // per-b scratch: z1 409600 + z1upT 4132864 + z2t 4132864 = 8675328 floats
    int bc = 16;
    while (bc > 1 && (size_t)bc * 8675328ull > avail) bc >>= 1;
    long long mc_ll = (long long)(avail / 3232ull);
    int mc = (int)((mc_ll / 128) * 128);
    if (mc < 128) mc = 128;
    if (mc > 12800) mc = 12800;

    k_zero<<<8, 256, 0, stream>>>(ws + OFF_SCAL);
    k_wtrans<<<(30720+255)/256, 256, 0, stream>>>(e1w,  ws + OFF_WT1,  20,  3, 512, 30720);
    k_wprep2a<<<(512*2560+255)/256, 256, 0, stream>>>(e2aw, (unsigned short*)(ws + OFF_WT2A));
    k_wprep2b<<<(128*3584+255)/256, 256, 0, stream>>>(e2bw, (unsigned short*)(ws + OFF_WT2B));
    k_wexpand2a<<<(NN1_*KP1_+255)/256, 256, 0, stream>>>(d1w, (unsigned short*)(ws + OFF_W1E));
    k_wexpand2<<<(NN2_*KP2_+255)/256, 256, 0, stream>>>(d2w, (unsigned short*)(ws + OFF_W2E), 512, 3, KP2_, NN2_*KP2_);
    k_cbprep<<<16, 256, 0, stream>>>(cbks, (unsigned short*)(ws + OFF_CBT), cnormd, ws + OFF_CNF);
    k_buildx<<<(256000+255)/256, 256, 0, stream>>>(traj, ws + OFF_X1);

    float* z1c  = ws + OFF_SCR;
    float* zupf = z1c + (size_t)bc * 409600;            // z1upT: bc * 4132864 floats (u16 x2)
    float* z2tf = zupf + (size_t)bc * 4132864;          // z2t:   bc * 4132864 floats (u16 x2)
    k_zpad2<<<(bc*9216+255)/256, 256, 0, stream>>>((unsigned short*)z2tf, bc);
    for (int b0 = 0; b0 < B_; b0 += bc){
        k_conv<3, true, false, 128><<<dim3(7, 4, bc), 256, 0, stream>>>(
            ws + OFF_X1 + (size_t)b0*20*TN_, ws + OFF_WT1, e1b, z1c, 20, 512, TN_);
        k_cumsum<<<(bc*512+63)/64, 64, 0, stream>>>(z1c, bc*512);
        k_upT<<<dim3((ZROWS_*512)/256, bc), 256, 0, stream>>>(z1c, (unsigned short*)zupf);
        k_mconv2a<<<dim3(63, 4, bc), 256, 0, stream>>>(
            (const unsigned short*)zupf, (const unsigned short*)(ws + OFF_WT2A), e2ab,
            (unsigned short*)z2tf);
        k_mconv2b<<<dim3(125, bc), 256, 0, stream>>>(
            (const unsigned short*)z2tf, (const unsigned short*)(ws + OFF_WT2B), e2bb,
            ws + OFF_ZE + (size_t)b0*T_*L_);
    }

    // ---- VQ phase: split screen/rotate (scratch reused: residG + top2G) ----
    float* residG = ws + OFF_SCR;                       // 16384000 floats
    float* top2G  = residG + 16384000ull;               // 512000 floats
    k_vqcopy<<<16000, 256, 0, stream>>>(ws + OFF_ZE, residG);
    for (int q = 0; q < Q_; ++q){
        k_vqscreen<<<NTOK_/64, 256, 0, stream>>>(
            residG, (const unsigned short*)(ws + OFF_CBT), ws + OFF_CNF, top2G, q);
        k_vqrot<<<NTOK_/64, 256, 0, stream>>>(
            ws + OFF_ZE, residG, top2G, cnormd, cbks, codes_i, ws + OFF_SCAL,
            q, (q == Q_-1) ? 1 : 0);
    }

    k_smooth<<<(B_*(T_-1)+255)/256, 256, 0, stream>>>(codes_i, ws + OFF_SCAL);

    float* A1c = ws + OFF_SCR;
    float* Hc  = A1c + (size_t)mc * KP1_;
    for (int m0 = 0; m0 < NC_; m0 += mc){
        int M = (NC_ - m0 < mc) ? (NC_ - m0) : mc;
        int Mpad = ((M + 127) / 128) * 128;
        k_builda1b<<<(Mpad*KP1_+255)/256, 256, 0, stream>>>(ws + OFF_ZE, codes_i,
                                                            (unsigned short*)A1c, m0, M, Mpad);
        k_mgemm1<<<dim3(Mpad/128, NN1_/128), 256, 0, stream>>>(
            (const unsigned short*)A1c, (const unsigned short*)(ws + OFF_W1E), d1b,
            (unsigned short*)Hc);
        k_mgemm2rec<<<dim3(Mpad/128, NN2_/128), 256, 0, stream>>>(
            (const unsigned short*)Hc, (const unsigned short*)(ws + OFF_W2E), d2b,
            ws + OFF_ZE, ws + OFF_SCAL, M, m0);
    }

    k_codesout<<<(NTOK_*Q_+255)/256, 256, 0, stream>>>(codes_i, out);
    k_final<<<1, 64, 0, stream>>>(ws + OFF_SCAL, out);
    (void)in_sizes; (void)n_in; (void)out_size; (void)ws_size;
}

// Round 14
// 3279.817 us; speedup vs baseline: 1.0499x; 1.0499x over previous
//
#include <hip/hip_runtime.h>
#include <cstdint>
#include <cstddef>

// ---------------- problem constants ----------------
#define B_     16
#define T_     8000
#define TN_    800
#define HID_   512
#define L_     128
#define KCB_   1024
#define Q_     4
#define COUNT_ 1599
#define NC_    (B_*COUNT_)   // 25584
#define NTOK_  (B_*T_)       // 128000
#define EPSF   1e-12

// decoder GEMM dims
#define KP1_   672           // k' = u*132 + ci (660 meaningful), padded to 672
#define NN1_   2560
#define KP2_   2560
#define NN2_   640

// conv2a/2b MFMA dims
#define ZROWS_ 8072          // upsampled rows: t in [-2, 8069]; row = t + 2
#define ZROWU_ 1024          // u16 per row: [pl(2)][ci(512)]
#define Z2ROWS_ 8072ull      // z2t rows: row = t + 3, pads zeroed
#define Z2ROWU_ 1024ull

typedef float v2f __attribute__((ext_vector_type(2)));
typedef short s16x8 __attribute__((ext_vector_type(8)));
typedef float f32x4 __attribute__((ext_vector_type(4)));
#define PKFMA(a,b,c) __builtin_elementwise_fma((a),(b),(c))
#define MFMA16(a,b,c) __builtin_amdgcn_mfma_f32_16x16x32_bf16((a),(b),(c),0,0,0)

// ---------------- static workspace layout (float offsets) ----------------
#define OFF_WT1   0ull
#define OFF_WT2A  30720ull        // Wp2a bf16 planes [512co][2][2560] = 1310720 floats
#define OFF_WT2B  1341440ull      // Wp2b bf16 planes [128co][2][3584] = 458752 floats
#define OFF_W1E   1800192ull
#define OFF_W2E   3520512ull
#define OFF_CBT   5158912ull      // cbp bf16 planes [q][pl][kb][1024 codes][8] = 524288 floats
#define OFF_CNORM 5683200ull
#define OFF_CNF   5691392ull
#define OFF_SCAL  5695488ull
#define OFF_X1    5697536ull
#define OFF_CODES 5953536ull
#define OFF_ZE    6465536ull
#define OFF_SCR   22849536ull

// ---------------- helpers ----------------
__device__ inline float wred(float v){
    #pragma unroll
    for (int o = 32; o > 0; o >>= 1) v += __shfl_xor(v, o);
    return v;
}
__device__ inline double shflxor_d(double v, int m){
    int2 a = *(int2*)&v;
    a.x = __shfl_xor(a.x, m);
    a.y = __shfl_xor(a.y, m);
    return *(double*)&a;
}
__device__ inline double wredd(double v){
    #pragma unroll
    for (int o = 32; o > 0; o >>= 1) v += shflxor_d(v, o);
    return v;
}
__device__ inline double qred(double v){
    v += shflxor_d(v, 1);
    v += shflxor_d(v, 2);
    return v;
}
// split fp32 into bf16 hi/lo (RNE): x ~= hi + lo, |err| <= 2^-18 |x|
__device__ inline void bsplit(float x, unsigned short &h, unsigned short &l){
    unsigned u = __float_as_uint(x);
    unsigned hr = (u + 0x7fffu + ((u >> 16) & 1u)) >> 16;
    float hf = __uint_as_float(hr << 16);
    h = (unsigned short)hr;
    float r = x - hf;
    unsigned u2 = __float_as_uint(r);
    unsigned lr2 = (u2 + 0x7fffu + ((u2 >> 16) & 1u)) >> 16;
    l = (unsigned short)lr2;
}

// ---------------- small prep kernels ----------------
__global__ __launch_bounds__(256) void k_zero(float* s){
    s[blockIdx.x*256 + threadIdx.x] = 0.f;
}

__global__ __launch_bounds__(256) void k_wtrans(const float* __restrict__ w, float* __restrict__ wT,
                                                int Cin, int K, int CO, int total){
    int i = blockIdx.x*256 + threadIdx.x;
    if (i >= total) return;
    int ci = i / (K*CO); int r = i % (K*CO); int k = r / CO; int co = r % CO;
    wT[i] = w[((size_t)co*Cin + ci)*K + k];
}

// conv2a weights -> [co][pl][kdim = u*512 + ci] bf16 hi/lo planes
__global__ __launch_bounds__(256) void k_wprep2a(const float* __restrict__ w, unsigned short* __restrict__ Wp){
    int idx = blockIdx.x*256 + threadIdx.x;   // 512*2560
    if (idx >= 512*2560) return;
    int co = idx / 2560, kd = idx % 2560;
    int u = kd >> 9, ci = kd & 511;
    float v = w[((size_t)co*512 + ci)*5 + u];
    unsigned short h, l; bsplit(v, h, l);
    Wp[((size_t)co*2 + 0)*2560 + kd] = h;
    Wp[((size_t)co*2 + 1)*2560 + kd] = l;
}

// conv2b weights -> [co][pl][kdim = u*512 + ci] bf16 hi/lo planes (K=7)
__global__ __launch_bounds__(256) void k_wprep2b(const float* __restrict__ w, unsigned short* __restrict__ Wp){
    int idx = blockIdx.x*256 + threadIdx.x;   // 128*3584
    if (idx >= 128*3584) return;
    int co = idx / 3584, kd = idx % 3584;
    int u = kd / 512, ci = kd % 512;
    float v = w[((size_t)co*512 + ci)*7 + u];
    unsigned short h, l; bsplit(v, h, l);
    Wp[((size_t)co*2 + 0)*3584 + kd] = h;
    Wp[((size_t)co*2 + 1)*3584 + kd] = l;
}

// GEMM1 decoder weights -> [n][pl][k' = u*132 + ci] bf16 hi/lo (coalescing-friendly enum)
__global__ __launch_bounds__(256) void k_wexpand2a(const float* __restrict__ w, unsigned short* __restrict__ Bp){
    int idx = blockIdx.x*256 + threadIdx.x;   // NN1_*KP1_
    if (idx >= NN1_*KP1_) return;
    int n = idx / KP1_, k = idx % KP1_;
    float v = 0.f;
    if (k < 660){
        int u = k / 132, ci = k % 132;
        int co = n / 5, t = n % 5;
        int kk = u - t + 2;
        if (kk >= 0 && kk < 5) v = w[((size_t)co*132 + ci)*5 + kk];
    }
    unsigned short h, l; bsplit(v, h, l);
    Bp[((size_t)n*2 + 0)*KP1_ + k] = h;
    Bp[((size_t)n*2 + 1)*KP1_ + k] = l;
}

// GEMM2 decoder weights -> [n][pl][k = ci*5 + u] bf16 hi/lo (matches H layout)
__global__ __launch_bounds__(256) void k_wexpand2(const float* __restrict__ w, unsigned short* __restrict__ Bp,
                                                  int Cin, int K, int KP, int total){
    int idx = blockIdx.x*256 + threadIdx.x;
    if (idx >= total) return;
    int n = idx / KP, k = idx % KP;
    float v = 0.f;
    if (k < Cin*5){
        int ci = k / 5, u = k % 5;
        int co = n / 5, t = n % 5;
        int kk = u - t + (K-1)/2;
        if (kk >= 0 && kk < K) v = w[((size_t)co*Cin + ci)*K + kk];
    }
    unsigned short h, l; bsplit(v, h, l);
    Bp[((size_t)n*2 + 0)*KP + k] = h;
    Bp[((size_t)n*2 + 1)*KP + k] = l;
}

// codebook prep: norms (fp64+fp32) + bf16 hi/lo planes, K-fragment-interleaved
__global__ __launch_bounds__(256) void k_cbprep(const float* __restrict__ cb,
                                                unsigned short* __restrict__ cbp, double* __restrict__ cnorm,
                                                float* __restrict__ cnf){
    int i = blockIdx.x*256 + threadIdx.x;
    if (i >= Q_*KCB_) return;
    int q = i >> 10, k = i & 1023;
    const float* row = cb + (size_t)i * L_;
    double s = 0.0;
    for (int d = 0; d < L_; ++d){
        float v = row[d];
        s += (double)v * (double)v;
        unsigned short h, l; bsplit(v, h, l);
        int kb = d >> 3, e = d & 7;
        cbp[((((size_t)q*2 + 0)*16 + kb)*1024 + k)*8 + e] = h;
        cbp[((((size_t)q*2 + 1)*16 + kb)*1024 + k)*8 + e] = l;
    }
    cnorm[i] = s;
    cnf[i] = (float)s;
}

__global__ __launch_bounds__(256) void k_buildx(const float* __restrict__ traj, float* __restrict__ x1){
    int i = blockIdx.x*256 + threadIdx.x;
    if (i >= B_*20*TN_) return;
    int b = i / (20*TN_); int r = i % (20*TN_); int ci = r / TN_; int tn = r % TN_;
    int d = ci / 10, kk = ci % 10;
    x1[i] = traj[((size_t)b*2 + d)*T_ + tn*10 + kk];
}

// exact sequential fp32 cumsum-diff; reads z1 [ci][tn] rows, writes TRANSPOSED z1t [tn][ci]
// (coalesced writes: at each j, 64 lanes write 64 consecutive floats)
__global__ __launch_bounds__(64) void k_cumsumT(const float* __restrict__ z1, float* __restrict__ z1t,
                                                int rows){
    int row = blockIdx.x*64 + threadIdx.x;
    if (row >= rows) return;
    int lb = row >> 9, ci = row & 511;
    const float* p = z1 + (size_t)row * TN_;
    float* q = z1t + (size_t)lb*409600 + ci;
    float run = 0.f;
    float4 v = *(const float4*)&p[0];
    int j = 0;
    for (; j < TN_ - 4; j += 4){
        float4 vn = *(const float4*)&p[j + 4];
        float prev, o0, o1, o2, o3;
        prev = run; run += v.x; o0 = run - prev;
        prev = run; run += v.y; o1 = run - prev;
        prev = run; run += v.z; o2 = run - prev;
        prev = run; run += v.w; o3 = run - prev;
        q[(size_t)(j+0)*512] = o0;
        q[(size_t)(j+1)*512] = o1;
        q[(size_t)(j+2)*512] = o2;
        q[(size_t)(j+3)*512] = o3;
        v = vn;
    }
    {
        float prev, o0, o1, o2, o3;
        prev = run; run += v.x; o0 = run - prev;
        prev = run; run += v.y; o1 = run - prev;
        prev = run; run += v.z; o2 = run - prev;
        prev = run; run += v.w; o3 = run - prev;
        q[(size_t)(j+0)*512] = o0;
        q[(size_t)(j+1)*512] = o1;
        q[(size_t)(j+2)*512] = o2;
        q[(size_t)(j+3)*512] = o3;
    }
}

// upsample z1t (800, tn-major) -> 8000, token-major bf16 hi/lo planes; coalesced reads
__global__ __launch_bounds__(256) void k_upT(const float* __restrict__ z1t, unsigned short* __restrict__ Zt){
    int idx = blockIdx.x*256 + threadIdx.x;       // over ZROWS_*512
    int lb = blockIdx.y;
    int ci = idx & 511, row = idx >> 9;
    if (row >= ZROWS_) return;
    int t = row - 2;
    float v = 0.f;
    if (t >= 0 && t < T_){
        const float* zr = z1t + (size_t)lb*409600;
        float s = fmaxf(0.5f*(float)t - 0.25f, 0.f);
        int i0 = (int)s;
        float f = s - (float)i0;
        int i1 = min(i0 + 1, T_/2 - 1);
        v = zr[(size_t)(i0/5)*512 + ci]*(1.f - f) + zr[(size_t)(i1/5)*512 + ci]*f;
    }
    unsigned short h, l; bsplit(v, h, l);
    unsigned short* dst = Zt + (size_t)lb*((size_t)ZROWS_*ZROWU_) + (size_t)row*ZROWU_;
    dst[ci] = h;
    dst[512 + ci] = l;
}

// zero halo rows of z2t: rows 0..2 and 8003..8071
__global__ __launch_bounds__(256) void k_zpad2(unsigned short* __restrict__ z2t, int bc){
    int idx = blockIdx.x*256 + threadIdx.x;     // uint4 units, 9216 per lb
    int lb = idx / 9216;
    if (lb >= bc) return;
    int r = idx % 9216;
    int rid = r >> 7, off = r & 127;
    int row = (rid < 3) ? rid : (8000 + rid);
    uint4 z = make_uint4(0,0,0,0);
    *(uint4*)&z2t[(size_t)lb*(Z2ROWS_*Z2ROWU_) + (size_t)row*Z2ROWU_ + (size_t)off*8] = z;
}

// ---------------- generic tiled conv1d fp32 (conv1 only) ----------------
template<int K, bool RELU, bool UPS, int TT>
__global__ __launch_bounds__(256) void k_conv(const float* __restrict__ in, const float* __restrict__ wT,
                                              const float* __restrict__ bias, float* __restrict__ out,
                                              int Cin, int CO, int T){
    constexpr int P   = (K-1)/2;
    constexpr int TIN = TT + K - 1;
    constexpr int TINP = ((TIN + 3) & ~3) + 4;
    constexpr int NG  = TT/64;
    __shared__ float inS[8][TINP];
    __shared__ float wS[8][K][128];
    int b  = blockIdx.z;
    int t0 = blockIdx.x * TT;
    int co0 = blockIdx.y * 128;
    int tid = threadIdx.x, tx = tid & 15, ty = tid >> 4;
    v2f acc[8][NG*2];
    #pragma unroll
    for (int i = 0; i < 8; ++i)
        #pragma unroll
        for (int j = 0; j < NG*2; ++j) acc[i][j] = (v2f){0.f, 0.f};

    const int inrow = UPS ? (T/10) : T;
    const int i1cap = UPS ? (T/2 - 1) : 0;
    const float* inB = in + (size_t)b * Cin * inrow;

    for (int ci0 = 0; ci0 < Cin; ci0 += 8){
        __syncthreads();
        for (int idx = tid; idx < 8*TIN; idx += 256){
            int ci = idx / TIN, tt = idx % TIN;
            int t = t0 + tt - P;
            int cig = ci0 + ci;
            float v = 0.f;
            if (cig < Cin && t >= 0 && t < T){
                const float* row = inB + (size_t)cig * inrow;
                if (UPS){
                    float s = fmaxf(0.5f*(float)t - 0.25f, 0.f);
                    int i0 = (int)s;
                    float f = s - (float)i0;
                    int i1 = min(i0 + 1, i1cap);
                    v = row[i0/5]*(1.f - f) + row[i1/5]*f;
                } else {
                    v = row[t];
                }
            }
            inS[ci][tt] = v;
        }
        for (int idx = tid; idx < 8*K*32; idx += 256){
            int ci = idx / (K*32);
            int rr = idx % (K*32);
            int k = rr / 32, co4 = (rr & 31)*4;
            int cig = ci0 + ci;
            float4 v = make_float4(0.f,0.f,0.f,0.f);
            if (cig < Cin) v = *(const float4*)&wT[((size_t)cig*K + k)*CO + co0 + co4];
            *(float4*)&wS[ci][k][co4] = v;
        }
        __syncthreads();
        #pragma unroll 1
        for (int ci = 0; ci < 8; ++ci){
            float win[NG][8];
            #pragma unroll
            for (int g = 0; g < NG; ++g){
                float4 a0 = *(const float4*)&inS[ci][g*64 + tx*4];
                float4 a1 = *(const float4*)&inS[ci][g*64 + tx*4 + 4];
                win[g][0]=a0.x; win[g][1]=a0.y; win[g][2]=a0.z; win[g][3]=a0.w;
                win[g][4]=a1.x; win[g][5]=a1.y; win[g][6]=a1.z; win[g][7]=a1.w;
            }
            #pragma unroll
            for (int k = 0; k < K; ++k){
                v2f a2[NG*2];
                #pragma unroll
                for (int g = 0; g < NG; ++g){
                    a2[g*2+0] = (v2f){win[g][k+0], win[g][k+1]};
                    a2[g*2+1] = (v2f){win[g][k+2], win[g][k+3]};
                }
                float4 w0 = *(const float4*)&wS[ci][k][ty*4];
                float4 w1 = *(const float4*)&wS[ci][k][64 + ty*4];
                float w[8] = {w0.x,w0.y,w0.z,w0.w, w1.x,w1.y,w1.z,w1.w};
                #pragma unroll
                for (int i = 0; i < 8; ++i){
                    v2f wv = (v2f){w[i], w[i]};
                    #pragma unroll
                    for (int j = 0; j < NG*2; ++j)
                        acc[i][j] = PKFMA(wv, a2[j], acc[i][j]);
                }
            }
        }
    }
    #pragma unroll
    for (int i = 0; i < 8; ++i){
        int co = co0 + (i < 4 ? ty*4 + i : 64 + ty*4 + (i-4));
        float bv = bias[co];
        #pragma unroll
        for (int g = 0; g < NG; ++g){
            int t = t0 + g*64 + tx*4;
            if (t >= T) continue;
            float v0 = acc[i][g*2+0].x + bv;
            float v1 = acc[i][g*2+0].y + bv;
            float v2 = acc[i][g*2+1].x + bv;
            float v3 = acc[i][g*2+1].y + bv;
            if (RELU){ v0=fmaxf(v0,0.f); v1=fmaxf(v1,0.f); v2=fmaxf(v2,0.f); v3=fmaxf(v3,0.f); }
            *(float4*)&out[((size_t)b*CO + co)*T + t] = make_float4(v0,v1,v2,v3);
        }
    }
}

// ---------------- conv2a via MFMA bf16x3, u-shift staging, stride-40 LDS ----------------
__global__ __launch_bounds__(256) void k_mconv2a(const unsigned short* __restrict__ Zt,
                                                 const unsigned short* __restrict__ Wp,
                                                 const float* __restrict__ bias,
                                                 unsigned short* __restrict__ z2t){
    __shared__ unsigned short SH[20800];   // 41600 B; ZL[pl][132][40] at 0, WL[pl][128][40] at 10560
    int lb = blockIdx.z;
    int t0 = blockIdx.x * 128;
    int co0 = blockIdx.y * 128;
    int tid = threadIdx.x;
    int lane = tid & 63, wid = tid >> 6;
    int wr = wid >> 1, wc = wid & 1;
    int lr = lane & 15, lg = lane >> 4;
    const unsigned short* Zb = Zt + (size_t)lb*((size_t)ZROWS_*ZROWU_);   // row index = t + 2
    f32x4 acc[4][4];
    #pragma unroll
    for (int i = 0; i < 4; ++i)
        #pragma unroll
        for (int j = 0; j < 4; ++j) acc[i][j] = (f32x4){0.f,0.f,0.f,0.f};

    for (int ci0 = 0; ci0 < 512; ci0 += 32){
        __syncthreads();
        for (int idx = tid; idx < 1056; idx += 256){
            int row = idx >> 3, rem = idx & 7, pl = rem >> 2, qo = rem & 3;
            *(uint4*)&SH[pl*5280 + row*40 + qo*8] =
                *(const uint4*)&Zb[(size_t)(t0 + row)*ZROWU_ + (size_t)pl*512 + ci0 + qo*8];
        }
        for (int u = 0; u < 5; ++u){
            if (u) __syncthreads();
            #pragma unroll
            for (int p = 0; p < 4; ++p){
                int idx = p*256 + tid;
                int n = idx >> 3, rem = idx & 7, pl = rem >> 2, qo = rem & 3;
                *(uint4*)&SH[10560 + pl*5120 + n*40 + qo*8] =
                    *(const uint4*)&Wp[((size_t)(co0+n)*2 + pl)*2560 + u*512 + ci0 + qo*8];
            }
            __syncthreads();
            s16x8 w[2][4], z[2][4];
            #pragma unroll
            for (int pl = 0; pl < 2; ++pl)
                #pragma unroll
                for (int mi = 0; mi < 4; ++mi)
                    w[pl][mi] = *(const s16x8*)&SH[10560 + pl*5120 + (wr*64 + mi*16 + lr)*40 + lg*8];
            #pragma unroll
            for (int pl = 0; pl < 2; ++pl)
                #pragma unroll
                for (int ni = 0; ni < 4; ++ni)
                    z[pl][ni] = *(const s16x8*)&SH[pl*5280 + (wc*64 + ni*16 + lr + u)*40 + lg*8];
            #pragma unroll
            for (int mi = 0; mi < 4; ++mi)
                #pragma unroll
                for (int ni = 0; ni < 4; ++ni){
                    f32x4 c = acc[mi][ni];
                    c = MFMA16(w[0][mi], z[0][ni], c);
                    c = MFMA16(w[0][mi], z[1][ni], c);
                    c = MFMA16(w[1][mi], z[0][ni], c);
                    acc[mi][ni] = c;
                }
        }
    }
    // epilogue: relu+bias, bf16-split, LDS-transpose to [t][co], write token-major planes
    unsigned short* Zo = z2t + (size_t)lb*(Z2ROWS_*Z2ROWU_);
    #pragma unroll
    for (int pl = 0; pl < 2; ++pl){
        __syncthreads();
        #pragma unroll
        for (int mi = 0; mi < 4; ++mi){
            int cb = wr*64 + mi*16 + lg*4;
            #pragma unroll
            for (int ni = 0; ni < 4; ++ni){
                int tl = wc*64 + ni*16 + lr;
                #pragma unroll
                for (int r = 0; r < 4; ++r){
                    float v = fmaxf(acc[mi][ni][r] + bias[co0 + cb + r], 0.f);
                    unsigned short h, l; bsplit(v, h, l);
                    SH[tl*136 + cb + r] = pl ? l : h;
                }
            }
        }
        __syncthreads();
        int tl = tid >> 1, half = tid & 1;
        if (t0 + tl < T_){
            uint4* dst = (uint4*)&Zo[((size_t)(t0 + tl + 3))*Z2ROWU_ + (size_t)pl*512 + co0 + half*64];
            const uint4* src = (const uint4*)&SH[tl*136 + half*64];
            #pragma unroll
            for (int e = 0; e < 8; ++e) dst[e] = src[e];
        }
    }
}

// ---------------- conv2b via MFMA bf16x3, TT=64, stride-40 LDS ----------------
__global__ __launch_bounds__(256) void k_mconv2b(const unsigned short* __restrict__ Z2,
                                                 const unsigned short* __restrict__ Wp,
                                                 const float* __restrict__ bias,
                                                 float* __restrict__ ze){
    __shared__ unsigned short SH[15840];   // 31680 B; ZL[pl][70][40] at 0, WL[pl][128][40] at 5600
    int lb = blockIdx.y;
    int t0 = blockIdx.x * 64;
    int tid = threadIdx.x;
    int lane = tid & 63, wid = tid >> 6;
    int lr = lane & 15, lg = lane >> 4;
    const unsigned short* Zb = Z2 + (size_t)lb*(Z2ROWS_*Z2ROWU_);
    f32x4 acc[2][4];
    #pragma unroll
    for (int i = 0; i < 2; ++i)
        #pragma unroll
        for (int j = 0; j < 4; ++j) acc[i][j] = (f32x4){0.f,0.f,0.f,0.f};

    for (int ci0 = 0; ci0 < 512; ci0 += 32){
        __syncthreads();
        for (int idx = tid; idx < 560; idx += 256){
            int row = idx >> 3, rem = idx & 7, pl = rem >> 2, qo = rem & 3;
            *(uint4*)&SH[pl*2800 + row*40 + qo*8] =
                *(const uint4*)&Zb[(size_t)(t0 + row)*Z2ROWU_ + (size_t)pl*512 + ci0 + qo*8];
        }
        for (int u = 0; u < 7; ++u){
            if (u) __syncthreads();
            #pragma unroll
            for (int p = 0; p < 4; ++p){
                int idx = p*256 + tid;
                int n = idx >> 3, rem = idx & 7, pl = rem >> 2, qo = rem & 3;
                *(uint4*)&SH[5600 + pl*5120 + n*40 + qo*8] =
                    *(const uint4*)&Wp[((size_t)n*2 + pl)*3584 + u*512 + ci0 + qo*8];
            }
            __syncthreads();
            s16x8 w[2][2], z[2][4];
            #pragma unroll
            for (int pl = 0; pl < 2; ++pl)
                #pragma unroll
                for (int mi = 0; mi < 2; ++mi)
                    w[pl][mi] = *(const s16x8*)&SH[5600 + pl*5120 + (wid*32 + mi*16 + lr)*40 + lg*8];
            #pragma unroll
            for (int pl = 0; pl < 2; ++pl)
                #pragma unroll
                for (int ni = 0; ni < 4; ++ni)
                    z[pl][ni] = *(const s16x8*)&SH[pl*2800 + (ni*16 + lr + u)*40 + lg*8];
            #pragma unroll
            for (int mi = 0; mi < 2; ++mi)
                #pragma unroll
                for (int ni = 0; ni < 4; ++ni){
                    f32x4 c = acc[mi][ni];
                    c = MFMA16(w[0][mi], z[0][ni], c);
                    c = MFMA16(w[0][mi], z[1][ni], c);
                    c = MFMA16(w[1][mi], z[0][ni], c);
                    acc[mi][ni] = c;
                }
        }
    }
    #pragma unroll
    for (int mi = 0; mi < 2; ++mi){
        int cb = wid*32 + mi*16 + lg*4;
        float4 bv = *(const float4*)&bias[cb];
        #pragma unroll
        for (int ni = 0; ni < 4; ++ni){
            int t = t0 + ni*16 + lr;
            float4 o;
            o.x = acc[mi][ni][0] + bv.x;
            o.y = acc[mi][ni][1] + bv.y;
            o.z = acc[mi][ni][2] + bv.z;
            o.w = acc[mi][ni][3] + bv.w;
            *(float4*)&ze[((size_t)lb*T_ + t)*L_ + cb] = o;
        }
    }
}

// ---------------- MFMA GEMM1: H = relu(A·B + bias[n/5]), bf16x3 split ----------------
__global__ __launch_bounds__(256) void k_mgemm1(const unsigned short* __restrict__ Ap,
                                                const unsigned short* __restrict__ Bp,
                                                const float* __restrict__ bias,
                                                unsigned short* __restrict__ Hp){
    __shared__ unsigned short AL[2][128][40];
    __shared__ unsigned short BL[2][128][40];
    int m0 = blockIdx.x * 128, n0 = blockIdx.y * 128;
    int tid = threadIdx.x;
    int lane = tid & 63, wid = tid >> 6;
    int wr = wid >> 1, wc = wid & 1;
    int lr = lane & 15, lg = lane >> 4;
    f32x4 acc[4][4];
    #pragma unroll
    for (int i = 0; i < 4; ++i)
        #pragma unroll
        for (int j = 0; j < 4; ++j) acc[i][j] = (f32x4){0.f,0.f,0.f,0.f};

    for (int kb = 0; kb < KP1_; kb += 32){
        __syncthreads();
        #pragma unroll
        for (int p = 0; p < 4; ++p){
            int slot = p*256 + tid;
            int m = slot >> 3, pl = (slot >> 2) & 1, q = slot & 3;
            uint4 v = *(const uint4*)&Ap[((size_t)(m0+m)*2 + pl)*KP1_ + kb + q*8];
            *(uint4*)&AL[pl][m][q*8] = v;
        }
        #pragma unroll
        for (int p = 0; p < 4; ++p){
            int slot = p*256 + tid;
            int n = slot >> 3, pl = (slot >> 2) & 1, q = slot & 3;
            uint4 v = *(const uint4*)&Bp[((size_t)(n0+n)*2 + pl)*KP1_ + kb + q*8];
            *(uint4*)&BL[pl][n][q*8] = v;
        }
        __syncthreads();
        s16x8 a[2][4], b[2][4];
        #pragma unroll
        for (int pl = 0; pl < 2; ++pl)
            #pragma unroll
            for (int mi = 0; mi < 4; ++mi)
                a[pl][mi] = *(const s16x8*)&AL[pl][wr*64 + mi*16 + lr][lg*8];
        #pragma unroll
        for (int pl = 0; pl < 2; ++pl)
            #pragma unroll
            for (int ni = 0; ni < 4; ++ni)
                b[pl][ni] = *(const s16x8*)&BL[pl][wc*64 + ni*16 + lr][lg*8];
        #pragma unroll
        for (int mi = 0; mi < 4; ++mi)
            #pragma unroll
            for (int ni = 0; ni < 4; ++ni){
                f32x4 c = acc[mi][ni];
                c = MFMA16(a[0][mi], b[0][ni], c);
                c = MFMA16(a[0][mi], b[1][ni], c);
                c = MFMA16(a[1][mi], b[0][ni], c);
                acc[mi][ni] = c;
            }
    }
    #pragma unroll
    for (int mi = 0; mi < 4; ++mi){
        int mbase = m0 + wr*64 + mi*16 + lg*4;
        #pragma unroll
        for (int ni = 0; ni < 4; ++ni){
            int n = n0 + wc*64 + ni*16 + lr;
            float bv = bias[n/5];
            #pragma unroll
            for (int r = 0; r < 4; ++r){
                float v = fmaxf(acc[mi][ni][r] + bv, 0.f);
                unsigned short h, l; bsplit(v, h, l);
                size_t m = (size_t)(mbase + r);
                Hp[(m*2 + 0)*NN1_ + n] = h;
                Hp[(m*2 + 1)*NN1_ + n] = l;
            }
        }
    }
}

// ---------------- MFMA GEMM2 + fused recon loss, bf16x3 split ----------------
__global__ __launch_bounds__(256) void k_mgemm2rec(const unsigned short* __restrict__ Ap,
                                                   const unsigned short* __restrict__ Bp,
                                                   const float* __restrict__ bias,
                                                   const float* __restrict__ zeq, float* __restrict__ scal,
                                                   int M, int m0g){
    __shared__ unsigned short AL[2][128][40];
    __shared__ unsigned short BL[2][128][40];
    int m0 = blockIdx.x * 128, n0 = blockIdx.y * 128;
    int tid = threadIdx.x;
    int lane = tid & 63, wid = tid >> 6;
    int wr = wid >> 1, wc = wid & 1;
    int lr = lane & 15, lg = lane >> 4;
    f32x4 acc[4][4];
    #pragma unroll
    for (int i = 0; i < 4; ++i)
        #pragma unroll
        for (int j = 0; j < 4; ++j) acc[i][j] = (f32x4){0.f,0.f,0.f,0.f};

    for (int kb = 0; kb < KP2_; kb += 32){
        __syncthreads();
        #pragma unroll
        for (int p = 0; p < 4; ++p){
            int slot = p*256 + tid;
            int m = slot >> 3, pl = (slot >> 2) & 1, q = slot & 3;
            uint4 v = *(const uint4*)&Ap[((size_t)(m0+m)*2 + pl)*KP2_ + kb + q*8];
            *(uint4*)&AL[pl][m][q*8] = v;
        }
        #pragma unroll
        for (int p = 0; p < 4; ++p){
            int slot = p*256 + tid;
            int n = slot >> 3, pl = (slot >> 2) & 1, q = slot & 3;
            uint4 v = *(const uint4*)&Bp[((size_t)(n0+n)*2 + pl)*KP2_ + kb + q*8];
            *(uint4*)&BL[pl][n][q*8] = v;
        }
        __syncthreads();
        s16x8 a[2][4], b[2][4];
        #pragma unroll
        for (int pl = 0; pl < 2; ++pl)
            #pragma unroll
            for (int mi = 0; mi < 4; ++mi)
                a[pl][mi] = *(const s16x8*)&AL[pl][wr*64 + mi*16 + lr][lg*8];
        #pragma unroll
        for (int pl = 0; pl < 2; ++pl)
            #pragma unroll
            for (int ni = 0; ni < 4; ++ni)
                b[pl][ni] = *(const s16x8*)&BL[pl][wc*64 + ni*16 + lr][lg*8];
        #pragma unroll
        for (int mi = 0; mi < 4; ++mi)
            #pragma unroll
            for (int ni = 0; ni < 4; ++ni){
                f32x4 c = acc[mi][ni];
                c = MFMA16(a[0][mi], b[0][ni], c);
                c = MFMA16(a[0][mi], b[1][ni], c);
                c = MFMA16(a[1][mi], b[0][ni], c);
                acc[mi][ni] = c;
            }
    }
    float lsum = 0.f;
    #pragma unroll
    for (int mi = 0; mi < 4; ++mi){
        #pragma unroll
        for (int r = 0; r < 4; ++r){
            int ml = wr*64 + mi*16 + lg*4 + r;
            int mlg = m0 + ml;
            if (mlg >= M) continue;
            int gm = m0g + mlg;
            int b = gm / COUNT_, c = gm % COUNT_;
            const float* tgtB = zeq + ((size_t)b*T_ + (size_t)(c+1)*5) * L_;
            #pragma unroll
            for (int ni = 0; ni < 4; ++ni){
                int n = n0 + wc*64 + ni*16 + lr;
                int co = n / 5, t = n % 5;
                float v = acc[mi][ni][r] + bias[co];
                float d = v - tgtB[(size_t)t*L_ + co];
                lsum += d*d;
            }
        }
    }
    lsum = wred(lsum);
    if (lane == 0) atomicAdd(&scal[1024 + ((blockIdx.x*5 + blockIdx.y) & 255)], lsum);
}

// ---------------- VQ phase v14: split screen/rotate kernels ----------------
__global__ __launch_bounds__(256) void k_vqcopy(const float* __restrict__ src, float* __restrict__ dst){
    size_t i = ((size_t)blockIdx.x*256 + threadIdx.x)*4;
    *(float4*)&dst[i] = *(const float4*)&src[i];
}

// screening: bf16x3 MFMA distances + per-token top-2 -> top2G (no rf LDS, no fp64)
__global__ __launch_bounds__(256, 2) void k_vqscreen(const float* __restrict__ resid,
                                                     const unsigned short* __restrict__ cbp,
                                                     const float* __restrict__ cnf,
                                                     float* __restrict__ top2, int q){
    __shared__ unsigned short rb[2][64][136];  // 34816 B residual bf16 hi/lo planes
    __shared__ float mvS[4][64][2];
    __shared__ int   miS[4][64][2];
    int tok0 = blockIdx.x * 64;
    int tid = threadIdx.x;
    int lane = tid & 63, wv = tid >> 6;
    int lr = lane & 15, lg = lane >> 4;
    int tok = tid >> 2, sub = tid & 3, dbase = sub*32;
    // phase 0: residual -> bf16 hi/lo planes (own slice, from global)
    {
        const float* zp = &resid[((size_t)(tok0 + tok))*L_ + dbase];
        #pragma unroll
        for (int j = 0; j < 4; ++j){
            float4 va = *(const float4*)&zp[j*8];
            float4 vb = *(const float4*)&zp[j*8 + 4];
            float rv[8] = {va.x,va.y,va.z,va.w, vb.x,vb.y,vb.z,vb.w};
            unsigned hp[4], lp[4];
            #pragma unroll
            for (int e = 0; e < 4; ++e){
                unsigned short h0,l0,h1,l1;
                bsplit(rv[e*2+0], h0, l0);
                bsplit(rv[e*2+1], h1, l1);
                hp[e] = (unsigned)h0 | ((unsigned)h1 << 16);
                lp[e] = (unsigned)l0 | ((unsigned)l1 << 16);
            }
            *(uint4*)&rb[0][tok][dbase + j*8] = make_uint4(hp[0],hp[1],hp[2],hp[3]);
            *(uint4*)&rb[1][tok][dbase + j*8] = make_uint4(lp[0],lp[1],lp[2],lp[3]);
        }
    }
    __syncthreads();
    // phase 1: screening GEMM; wave wv owns codes [wv*256, +256), 8 chunks of 32
    const unsigned short* cq = cbp + (size_t)q*(2*16*1024*8);
    const float* cnq = cnf + (size_t)q*KCB_;
    int code0w = wv*256;
    float m1[4], m2[4]; int i1[4], i2[4];
    #pragma unroll
    for (int t = 0; t < 4; ++t){ m1[t]=3.4e38f; m2[t]=3.4e38f; i1[t]=0x7fffffff; i2[t]=0x7fffffff; }
    for (int ch = 0; ch < 8; ++ch){
        f32x4 acc[2][4];
        #pragma unroll
        for (int i = 0; i < 2; ++i)
            #pragma unroll
            for (int j = 0; j < 4; ++j) acc[i][j] = (f32x4){0.f,0.f,0.f,0.f};
        #pragma unroll
        for (int ks = 0; ks < 4; ++ks){
            s16x8 b0[4], b1[4];
            #pragma unroll
            for (int tf = 0; tf < 4; ++tf){
                b0[tf] = *(const s16x8*)&rb[0][tf*16 + lr][ks*32 + lg*8];
                b1[tf] = *(const s16x8*)&rb[1][tf*16 + lr][ks*32 + lg*8];
            }
            #pragma unroll
            for (int mi = 0; mi < 2; ++mi){
                s16x8 a0 = *(const s16x8*)&cq[((size_t)(0*16 + ks*4 + lg)*1024
                                               + code0w + ch*32 + mi*16 + lr)*8];
                s16x8 a1 = *(const s16x8*)&cq[((size_t)(1*16 + ks*4 + lg)*1024
                                               + code0w + ch*32 + mi*16 + lr)*8];
                #pragma unroll
                for (int tf = 0; tf < 4; ++tf){
                    f32x4 c = acc[mi][tf];
                    c = MFMA16(a0, b0[tf], c);
                    c = MFMA16(a0, b1[tf], c);
                    c = MFMA16(a1, b0[tf], c);
                    acc[mi][tf] = c;
                }
            }
        }
        // selection: code = code0w + ch*32 + mi*16 + lg*4 + rr (monotone per lane)
        #pragma unroll
        for (int mi = 0; mi < 2; ++mi){
            float4 cn4 = *(const float4*)&cnq[code0w + ch*32 + mi*16 + lg*4];
            float cnv[4] = {cn4.x, cn4.y, cn4.z, cn4.w};
            #pragma unroll
            for (int tf = 0; tf < 4; ++tf)
                #pragma unroll
                for (int rr = 0; rr < 4; ++rr){
                    float sc = cnv[rr] - 2.f*acc[mi][tf][rr];
                    int code = code0w + ch*32 + mi*16 + lg*4 + rr;
                    bool c1 = sc < m1[tf];
                    bool c2 = sc < m2[tf];
                    if (c1){ m2[tf]=m1[tf]; i2[tf]=i1[tf]; m1[tf]=sc; i1[tf]=code; }
                    else if (c2){ m2[tf]=sc; i2[tf]=code; }
                }
        }
    }
    // cross-lane merge over lg groups (xor 16, 32)
    #pragma unroll
    for (int tf = 0; tf < 4; ++tf){
        float a1 = m1[tf], a2 = m2[tf]; int ai1 = i1[tf], ai2 = i2[tf];
        #pragma unroll
        for (int m = 16; m <= 32; m <<= 1){
            float o1 = __shfl_xor(a1, m), o2 = __shfl_xor(a2, m);
            int oi1 = __shfl_xor(ai1, m), oi2 = __shfl_xor(ai2, m);
            bool sw = (o1 < a1) || (o1 == a1 && oi1 < ai1);
            float w1 = sw ? o1 : a1;  int wi1 = sw ? oi1 : ai1;
            float l1 = sw ? a1 : o1;  int li1 = sw ? ai1 : oi1;
            float w2 = sw ? o2 : a2;  int wi2 = sw ? oi2 : ai2;
            bool s2 = (l1 < w2) || (l1 == w2 && li1 < wi2);
            a1 = w1; ai1 = wi1;
            a2 = s2 ? l1 : w2; ai2 = s2 ? li1 : wi2;
        }
        if (lg == 0){
            mvS[wv][tf*16 + lr][0] = a1; mvS[wv][tf*16 + lr][1] = a2;
            miS[wv][tf*16 + lr][0] = ai1; miS[wv][tf*16 + lr][1] = ai2;
        }
    }
    __syncthreads();
    // final merge across 4 waves; one writer per token
    if (tid < 64){
        float a1 = mvS[0][tid][0], a2 = mvS[0][tid][1];
        int ai1 = miS[0][tid][0], ai2 = miS[0][tid][1];
        #pragma unroll
        for (int w = 1; w < 4; ++w){
            float o1 = mvS[w][tid][0], o2 = mvS[w][tid][1];
            int oi1 = miS[w][tid][0], oi2 = miS[w][tid][1];
            bool sw = (o1 < a1) || (o1 == a1 && oi1 < ai1);
            float w1 = sw ? o1 : a1;  int wi1 = sw ? oi1 : ai1;
            float l1 = sw ? a1 : o1;  int li1 = sw ? ai1 : oi1;
            float w2 = sw ? o2 : a2;  int wi2 = sw ? oi2 : ai2;
            bool s2 = (l1 < w2) || (l1 == w2 && li1 < wi2);
            a1 = w1; ai1 = wi1;
            a2 = s2 ? l1 : w2; ai2 = s2 ? li1 : wi2;
        }
        float* t2 = &top2[((size_t)(tok0 + tid))*4];
        t2[0] = a1; t2[1] = a2;
        ((int*)t2)[2] = ai1; ((int*)t2)[3] = ai2;
    }
}

// rotation: fp64 recheck + rotate-to + commit loss + codes; residual in registers
__global__ __launch_bounds__(256, 2) void k_vqrot(float* __restrict__ ze, float* __restrict__ resid,
                                                  const float* __restrict__ top2,
                                                  const double* __restrict__ cnorm,
                                                  const float* __restrict__ cb,
                                                  int* __restrict__ codes, float* __restrict__ scal,
                                                  int q, int last){
    int tok0 = blockIdx.x * 64;
    int tid = threadIdx.x;
    int tok = tid >> 2, sub = tid & 3, dbase = sub*32;
    float r[32];
    {
        const float* zp = &resid[((size_t)(tok0 + tok))*L_ + dbase];
        #pragma unroll
        for (int h = 0; h < 8; ++h){
            float4 v = *(const float4*)&zp[h*4];
            r[h*4+0]=v.x; r[h*4+1]=v.y; r[h*4+2]=v.z; r[h*4+3]=v.w;
        }
    }
    const float* t2 = &top2[((size_t)(tok0 + tok))*4];
    float a1 = t2[0], a2 = t2[1];
    int id = ((const int*)t2)[2];
    int idb = (a2 - a1 < 0.1f) ? ((const int*)t2)[3] : -1;

    const float* cbq  = cb + (size_t)q*KCB_*L_;
    const double* cnq64 = cnorm + (size_t)q*KCB_;
    if (idb >= 0){
        const float* c1p = cbq + (size_t)id * L_ + dbase;
        const float* c2p = cbq + (size_t)idb * L_ + dbase;
        double p1 = 0.0, p2 = 0.0;
        #pragma unroll
        for (int h = 0; h < 8; ++h){
            float4 a4 = *(const float4*)&c1p[h*4];
            float4 b4 = *(const float4*)&c2p[h*4];
            float ca[4] = {a4.x,a4.y,a4.z,a4.w};
            float cbv[4] = {b4.x,b4.y,b4.z,b4.w};
            #pragma unroll
            for (int e = 0; e < 4; ++e){
                double rv = (double)r[h*4 + e];
                p1 = fma(rv, (double)ca[e], p1);
                p2 = fma(rv, (double)cbv[e], p2);
            }
        }
        p1 = qred(p1); p2 = qred(p2);
        double d1 = cnq64[id]  - 2.0*p1;
        double d2 = cnq64[idb] - 2.0*p2;
        if (d2 < d1 || (d2 == d1 && idb < id)) id = idb;
    }
    if (sub == 0) codes[((size_t)(tok0 + tok))*Q_ + q] = id;

    const float* cp = cbq + (size_t)id * L_ + dbase;
    double srr = 0.0, scc = 0.0, src = 0.0;
    #pragma unroll
    for (int h = 0; h < 8; ++h){
        float4 c4 = *(const float4*)&cp[h*4];
        float cvs[4] = {c4.x,c4.y,c4.z,c4.w};
        #pragma unroll
        for (int e = 0; e < 4; ++e){
            double rd = (double)r[h*4 + e];
            double cd = (double)cvs[e];
            srr = fma(rd, rd, srr);
            scc = fma(cd, cd, scc);
            src = fma(rd, cd, src);
        }
    }
    srr = qred(srr); scc = qred(scc); src = qred(src);
    double ns = sqrt(srr), nt = sqrt(scc);
    double insp = 1.0/(ns + EPSF), intp = 1.0/(nt + EPSF);
    double sn2 = srr*insp*insp + 2.0*src*insp*intp + scc*intp*intp;
    double isn = 1.0/(sqrt(sn2) + EPSF);
    double ew = (srr*insp + src*intp)*isn;
    double eu = srr*insp;
    double scale = nt*insp;
    double clp = 0.0;
    #pragma unroll
    for (int h = 0; h < 8; ++h){
        float4 c4 = *(const float4*)&cp[h*4];
        float cvs[4] = {c4.x,c4.y,c4.z,c4.w};
        #pragma unroll
        for (int e = 0; e < 4; ++e){
            float rf32 = r[h*4 + e];
            double rv = (double)rf32, cd = (double)cvs[e];
            double wd = (rv*insp + cd*intp)*isn;
            double qd = cd*intp;
            float qr = (float)((rv - 2.0*ew*wd + 2.0*eu*qd)*scale);
            r[h*4 + e] = rf32 - qr;
            float dd = cvs[e] - rf32;
            clp += (double)(dd*dd);
        }
    }
    clp = qred(clp);
    double cl = (sub == 0) ? clp : 0.0;
    cl = wredd(cl);
    if ((tid & 63) == 0) atomicAdd(&scal[q*256 + (blockIdx.x & 255)], (float)cl);

    if (!last){
        float* rp = &resid[((size_t)(tok0 + tok))*L_ + dbase];
        #pragma unroll
        for (int h = 0; h < 8; ++h)
            *(float4*)&rp[h*4] = make_float4(r[h*4+0], r[h*4+1], r[h*4+2], r[h*4+3]);
    } else {
        float* zw = &ze[((size_t)(tok0 + tok))*L_ + dbase];
        #pragma unroll
        for (int h = 0; h < 8; ++h){
            float4 o = *(float4*)&zw[h*4];
            o.x -= r[h*4+0];
            o.y -= r[h*4+1];
            o.z -= r[h*4+2];
            o.w -= r[h*4+3];
            *(float4*)&zw[h*4] = o;
        }
    }
}

// ---------------- losses / decoder glue ----------------
__global__ __launch_bounds__(256) void k_smooth(const int* __restrict__ codes, float* __restrict__ scal){
    int i = blockIdx.x*256 + threadIdx.x;
    float v = 0.f;
    if (i < B_*(T_-1)){
        int b = i / (T_-1), t = i % (T_-1);
        int c0 = codes[((size_t)b*T_ + t)*Q_];
        int c1 = codes[((size_t)b*T_ + t + 1)*Q_];
        v = (c0 != c1) ? 1.f : 0.f;
    }
    v = wred(v);
    if ((threadIdx.x & 63) == 0) atomicAdd(&scal[1280 + (blockIdx.x & 255)], v);
}

// build A1 hi/lo bf16 planes [m][pl][k' = u*132 + ci]; coalesced zeq reads + A1 writes
__global__ __launch_bounds__(256) void k_builda1b(const float* __restrict__ zeq,
                                                  const int* __restrict__ codes, unsigned short* __restrict__ A1,
                                                  int m0, int M, int Mpad){
    int i = blockIdx.x*256 + threadIdx.x;
    if (i >= Mpad*KP1_) return;
    int ml = i / KP1_, k = i % KP1_;
    float v = 0.f;
    if (ml < M && k < 660){
        int u = k / 132, ci = k % 132;
        int gm = m0 + ml;
        int b = gm / COUNT_, c = gm % COUNT_;
        int t = c*5 + u;
        if (ci < L_) v = zeq[((size_t)b*T_ + t)*L_ + ci];
        else         v = (float)codes[((size_t)b*T_ + t)*Q_ + (ci - L_)];
    }
    unsigned short h, l; bsplit(v, h, l);
    A1[((size_t)ml*2 + 0)*KP1_ + k] = h;
    A1[((size_t)ml*2 + 1)*KP1_ + k] = l;
}

__global__ __launch_bounds__(256) void k_codesout(const int* __restrict__ codes, float* __restrict__ out){
    int i = blockIdx.x*256 + threadIdx.x;
    if (i < NTOK_*Q_) out[i] = (float)codes[i];
}

__global__ __launch_bounds__(64) void k_final(const float* __restrict__ scal, float* __restrict__ out){
    if (threadIdx.x != 0) return;
    double s[4] = {0,0,0,0};
    double rec = 0, sm = 0;
    for (int i = 0; i < 256; ++i){
        s[0] += scal[i]; s[1] += scal[256+i]; s[2] += scal[512+i]; s[3] += scal[768+i];
        rec += scal[1024+i]; sm += scal[1280+i];
    }
    double denom = 16384000.0;
    double vq = (s[0]/denom + s[1]/denom + s[2]/denom + s[3]/denom) / 4.0;
    double recon = rec / 16373760.0;
    double smooth = sm / 127984.0;
    double loss = recon + vq + 0.1*smooth;
    out[512000] = (float)loss;
    out[512001] = (float)recon;
    out[512002] = (float)vq;
    out[512003] = (float)smooth;
}

// ---------------- launch ----------------
extern "C" void kernel_launch(void* const* d_in, const int* in_sizes, int n_in,
                              void* d_out, int out_size, void* d_ws, size_t ws_size,
                              hipStream_t stream) {
    const float* traj = (const float*)d_in[0];
    const float* e1w  = (const float*)d_in[2];
    const float* e1b  = (const float*)d_in[3];
    const float* e2aw = (const float*)d_in[4];
    const float* e2ab = (const float*)d_in[5];
    const float* e2bw = (const float*)d_in[6];
    const float* e2bb = (const float*)d_in[7];
    const float* d1w  = (const float*)d_in[8];
    const float* d1b  = (const float*)d_in[9];
    const float* d2w  = (const float*)d_in[10];
    const float* d2b  = (const float*)d_in[11];
    const float* cbks = (const float*)d_in[12];
    float* out = (float*)d_out;
    float* ws  = (float*)d_ws;
    int* codes_i = (int*)(ws + OFF_CODES);
    double* cnormd = (double*)(ws + OFF_CNORM);

    size_t wsf = ws_size / 4;
    size_t avail = (wsf > OFF_SCR) ? (wsf - OFF_SCR) : 0;
    // per-b scratch: z1 409600 + z1t 409600 + z1upT 4132864 + z2t 4132864 = 9084928 floats
    int bc = 16;
    while (bc > 1 && (size_t)bc * 9084928ull > avail) bc >>= 1;
    long long mc_ll = (long long)(avail / 3232ull);
    int mc = (int)((mc_ll / 128) * 128);
    if (mc < 128) mc = 128;
    if (mc > 12800) mc = 12800;

    k_zero<<<8, 256, 0, stream>>>(ws + OFF_SCAL);
    k_wtrans<<<(30720+255)/256, 256, 0, stream>>>(e1w,  ws + OFF_WT1,  20,  3, 512, 30720);
    k_wprep2a<<<(512*2560+255)/256, 256, 0, stream>>>(e2aw, (unsigned short*)(ws + OFF_WT2A));
    k_wprep2b<<<(128*3584+255)/256, 256, 0, stream>>>(e2bw, (unsigned short*)(ws + OFF_WT2B));
    k_wexpand2a<<<(NN1_*KP1_+255)/256, 256, 0, stream>>>(d1w, (unsigned short*)(ws + OFF_W1E));
    k_wexpand2<<<(NN2_*KP2_+255)/256, 256, 0, stream>>>(d2w, (unsigned short*)(ws + OFF_W2E), 512, 3, KP2_, NN2_*KP2_);
    k_cbprep<<<16, 256, 0, stream>>>(cbks, (unsigned short*)(ws + OFF_CBT), cnormd, ws + OFF_CNF);
    k_buildx<<<(256000+255)/256, 256, 0, stream>>>(traj, ws + OFF_X1);

    float* z1c  = ws + OFF_SCR;
    float* z1t  = z1c + (size_t)bc * 409600;            // transposed z1: [tn][ci]
    float* zupf = z1t + (size_t)bc * 409600;            // z1upT: bc * 4132864 floats (u16 x2)
    float* z2tf = zupf + (size_t)bc * 4132864;          // z2t:   bc * 4132864 floats (u16 x2)
    k_zpad2<<<(bc*9216+255)/256, 256, 0, stream>>>((unsigned short*)z2tf, bc);
    for (int b0 = 0; b0 < B_; b0 += bc){
        k_conv<3, true, false, 128><<<dim3(7, 4, bc), 256, 0, stream>>>(
            ws + OFF_X1 + (size_t)b0*20*TN_, ws + OFF_WT1, e1b, z1c, 20, 512, TN_);
        k_cumsumT<<<(bc*512+63)/64, 64, 0, stream>>>(z1c, z1t, bc*512);
        k_upT<<<dim3((ZROWS_*512)/256, bc), 256, 0, stream>>>(z1t, (unsigned short*)zupf);
        k_mconv2a<<<dim3(63, 4, bc), 256, 0, stream>>>(
            (const unsigned short*)zupf, (const unsigned short*)(ws + OFF_WT2A), e2ab,
            (unsigned short*)z2tf);
        k_mconv2b<<<dim3(125, bc), 256, 0, stream>>>(
            (const unsigned short*)z2tf, (const unsigned short*)(ws + OFF_WT2B), e2bb,
            ws + OFF_ZE + (size_t)b0*T_*L_);
    }

    // ---- VQ phase: split screen/rotate (scratch reused: residG + top2G) ----
    float* residG = ws + OFF_SCR;                       // 16384000 floats
    float* top2G  = residG + 16384000ull;               // 512000 floats
    k_vqcopy<<<16000, 256, 0, stream>>>(ws + OFF_ZE, residG);
    for (int q = 0; q < Q_; ++q){
        k_vqscreen<<<NTOK_/64, 256, 0, stream>>>(
            residG, (const unsigned short*)(ws + OFF_CBT), ws + OFF_CNF, top2G, q);
        k_vqrot<<<NTOK_/64, 256, 0, stream>>>(
            ws + OFF_ZE, residG, top2G, cnormd, cbks, codes_i, ws + OFF_SCAL,
            q, (q == Q_-1) ? 1 : 0);
    }

    k_smooth<<<(B_*(T_-1)+255)/256, 256, 0, stream>>>(codes_i, ws + OFF_SCAL);

    float* A1c = ws + OFF_SCR;
    float* Hc  = A1c + (size_t)mc * KP1_;
    for (int m0 = 0; m0 < NC_; m0 += mc){
        int M = (NC_ - m0 < mc) ? (NC_ - m0) : mc;
        int Mpad = ((M + 127) / 128) * 128;
        k_builda1b<<<(Mpad*KP1_+255)/256, 256, 0, stream>>>(ws + OFF_ZE, codes_i,
                                                            (unsigned short*)A1c, m0, M, Mpad);
        k_mgemm1<<<dim3(Mpad/128, NN1_/128), 256, 0, stream>>>(
            (const unsigned short*)A1c, (const unsigned short*)(ws + OFF_W1E), d1b,
            (unsigned short*)Hc);
        k_mgemm2rec<<<dim3(Mpad/128, NN2_/128), 256, 0, stream>>>(
            (const unsigned short*)Hc, (const unsigned short*)(ws + OFF_W2E), d2b,
            ws + OFF_ZE, ws + OFF_SCAL, M, m0);
    }

    k_codesout<<<(NTOK_*Q_+255)/256, 256, 0, stream>>>(codes_i, out);
    k_final<<<1, 64, 0, stream>>>(ws + OFF_SCAL, out);
    (void)in_sizes; (void)n_in; (void)out_size; (void)ws_size;
}